// Round 14
// baseline (1160.130 us; speedup 1.0000x reference)
//
#include <hip/hip_runtime.h>
#include <hip/hip_bf16.h>
#include <hip/hip_cooperative_groups.h>
#include <math.h>

namespace cg = cooperative_groups;

// Problem constants
#define BB 4
#define CIN 64
#define CH 32
#define NN 4096
#define NQCH 32
#define LOG2E 1.4426950408889634f
#define L2_10K 13.287712379549449f

// ws layout (floats). End = 2,278,400 floats = 8.69 MiB (ws >= 10.16 MiB proven).
#define Q4_OFF     1024
#define K4_OFF     66560
#define CV_OFF     132096
#define RMAP_OFF   148480
#define CMAPF_OFF  164864
#define T8_OFF     181248      // 2097152 (16 chunks x 8 per query)
#define CPSUM_OFF  181248      // aliases T8 head; dead before k3a
#define XA_OFF     181248      // aliases T8; written k4 (after k3b)
#define XB_OFF     705536      // aliases T8; written k5

// out layout (f32): x | out | corrected_map
#define OUT_X_OFF   0
#define OUT_O_OFF   524288
#define OUT_CM_OFF  540672

#define CE(x, y) { float ce_lo = fminf(x, y); y = fmaxf(x, y); x = ce_lo; }

__device__ __forceinline__ float bilin32(const float* src, int b, int y, int x) {
    float sy = 0.5f * y - 0.25f;
    float sx = 0.5f * x - 0.25f;
    float fy0 = floorf(sy), fx0 = floorf(sx);
    int y0 = (int)fy0, x0 = (int)fx0;
    float fy = sy - fy0, fx = sx - fx0;
    int y0c = min(max(y0, 0), 31), y1c = min(max(y0 + 1, 0), 31);
    int x0c = min(max(x0, 0), 31), x1c = min(max(x0 + 1, 0), 31);
    const float* p = src + b * 1024;
    float v00 = p[y0c * 32 + x0c], v01 = p[y0c * 32 + x1c];
    float v10 = p[y1c * 32 + x0c], v11 = p[y1c * 32 + x1c];
    float v0 = v00 + fx * (v01 - v00);
    float v1 = v10 + fx * (v11 - v10);
    return v0 + fy * (v1 - v0);
}

// ======================= MEGA (cooperative, 512 x 256) =======================
__global__ __launch_bounds__(256, 2) void mega(
        const float* __restrict__ f, const float* __restrict__ mapin,
        const float* __restrict__ f_q, const float* __restrict__ f_k,
        const float* __restrict__ m_k, const float* __restrict__ wq,
        const float* __restrict__ wk, const float* __restrict__ w_in,
        const float* __restrict__ b_in, const float* __restrict__ w_mid,
        const float* __restrict__ b_mid, const float* __restrict__ w_out,
        const float* __restrict__ b_out, float* __restrict__ outp,
        float* __restrict__ ws) {
    cg::grid_group gg = cg::this_grid();
    __shared__ __align__(16) char smem[46096];
    const int tid = threadIdx.x;
    const int bid = blockIdx.x;
    const int GD  = gridDim.x;   // 512

    float* Q4    = ws + Q4_OFF;
    float* K4    = ws + K4_OFF;
    float* CV    = ws + CV_OFF;
    float* CPSUM = ws + CPSUM_OFF;
    float* RMAP  = ws + RMAP_OFF;
    float* CMAPF = ws + CMAPF_OFF;
    float* T8    = ws + T8_OFF;
    float* XA    = ws + XA_OFF;
    float* XB    = ws + XB_OFF;

    // ---- stage 1: Q/K projection + fused pos table (512 vblocks of 32 q) ----
    {
        float* wqs = (float*)smem;              // 256 f
        float* wks = (float*)(smem + 1024);     // 256 f
        float* pp  = (float*)(smem + 2048);     // 1024 f
        float (*red)[9] = (float (*)[9])(smem + 6144);  // 256 x 9
        wqs[tid] = wq[tid];
        wks[tid] = wk[tid];
        __syncthreads();
        if (tid < 64) {
            float coord = (float)(tid + 1);
            float qy[4] = {0,0,0,0}, qx[4] = {0,0,0,0}, ky[4] = {0,0,0,0}, kx[4] = {0,0,0,0};
            for (int c = 0; c < 32; ++c) {
                float e = (2.0f * (float)(c >> 1)) * (1.0f / 32.0f);
                float ang = coord * exp2f(-e * L2_10K);
                float pr = (c & 1) ? cosf(ang) : sinf(ang);
                #pragma unroll
                for (int m = 0; m < 4; ++m) {
                    qy[m] += wqs[m * 64 + c] * pr;
                    qx[m] += wqs[m * 64 + 32 + c] * pr;
                    ky[m] += wks[m * 64 + c] * pr;
                    kx[m] += wks[m * 64 + 32 + c] * pr;
                }
            }
            #pragma unroll
            for (int m = 0; m < 4; ++m) {
                pp[0 * 256 + m * 64 + tid] = qy[m];
                pp[1 * 256 + m * 64 + tid] = qx[m];
                pp[2 * 256 + m * 64 + tid] = ky[m];
                pp[3 * 256 + m * 64 + tid] = kx[m];
            }
        }
        int qi = tid & 31, g = tid >> 5;       // 8 groups x 8 channels
        int gid = bid * 32 + qi;
        int b = gid >> 12, hw = gid & 4095;
        const float* fqb = f_q + (size_t)b * CIN * NN + hw;
        const float* fkb = f_k + (size_t)b * CIN * NN + hw;
        float aq[4] = {0,0,0,0}, ak[4] = {0,0,0,0};
        int c0 = g * 8;
        #pragma unroll
        for (int c = c0; c < c0 + 8; ++c) {
            float vq = fqb[c * NN];
            float vk = fkb[c * NN];
            #pragma unroll
            for (int m = 0; m < 4; ++m) {
                aq[m] += wqs[m * 64 + c] * vq;
                ak[m] += wks[m * 64 + c] * vk;
            }
        }
        #pragma unroll
        for (int m = 0; m < 4; ++m) { red[tid][m] = aq[m]; red[tid][4 + m] = ak[m]; }
        __syncthreads();
        if (tid < 32) {
            int y = hw >> 6, x = hw & 63;
            float q4v[4], k4v[4];
            #pragma unroll
            for (int m = 0; m < 4; ++m) {
                float sq = 0.0f, sk = 0.0f;
                #pragma unroll
                for (int j = 0; j < 8; ++j) {
                    sq += red[tid + 32 * j][m];
                    sk += red[tid + 32 * j][4 + m];
                }
                q4v[m] = LOG2E * (sq + pp[0 * 256 + m * 64 + y] + pp[1 * 256 + m * 64 + x]);
                k4v[m] = sk + pp[2 * 256 + m * 64 + y] + pp[3 * 256 + m * 64 + x];
            }
            ((float4*)Q4)[gid] = make_float4(q4v[0], q4v[1], q4v[2], q4v[3]);
            ((float4*)K4)[gid] = make_float4(k4v[0], k4v[1], k4v[2], k4v[3]);
        }
    }
    __threadfence(); gg.sync();

    // ---- stage 2: column sums (1024 vblocks, 2 keys/thread) ----
    for (int vb = bid; vb < 1024; vb += GD) {
        int kblk = vb & 7, qch = (vb >> 3) & 31, b = vb >> 8;
        const float4* Qg = (const float4*)Q4 + b * NN + qch * 128;  // uniform
        int kk = kblk * 512 + tid;
        float4 kva = ((const float4*)K4)[b * NN + kk];
        float4 kvb = ((const float4*)K4)[b * NN + kk + 256];
        float sa = 0.0f, sb = 0.0f;
        #pragma unroll 8
        for (int i = 0; i < 128; ++i) {
            float4 q = Qg[i];
            float da = fmaf(q.x, kva.x, fmaf(q.y, kva.y, fmaf(q.z, kva.z, q.w * kva.w)));
            float db = fmaf(q.x, kvb.x, fmaf(q.y, kvb.y, fmaf(q.z, kvb.z, q.w * kvb.w)));
            sa += exp2f(da);
            sb += exp2f(db);
        }
        CPSUM[(b * NQCH + qch) * NN + kk] = sa;
        CPSUM[(b * NQCH + qch) * NN + kk + 256] = sb;
    }
    __threadfence(); gg.sync();

    // ---- stage 3: merge sums -> c' (64 vblocks) ----
    for (int vb = bid; vb < 64; vb += GD) {
        int gid = vb * 256 + tid;
        int b = gid >> 12, k = gid & 4095;
        float S = 0.0f;
        #pragma unroll
        for (int j = 0; j < NQCH; ++j) S += CPSUM[(b * NQCH + j) * NN + k];
        float mk = bilin32(m_k, b, k >> 6, k & 63);
        CV[gid] = LOG2E * (mk - 1.0f) - log2f(S);
    }
    __threadfence(); gg.sync();

    // ---- stage 4: top-8 chunk scan (1024 vblocks; v4 body, scalar loads) ----
    for (int vb = bid; vb < 1024; vb += GD) {
        int kc = vb & 15, g4 = (vb >> 4) & 15, b = vb >> 8;
        int wave = tid >> 6, lane = tid & 63;
        int qrow = (g4 * 4 + wave) * 64 + lane;
        float4 qv = ((const float4*)Q4)[b * NN + qrow];
        const float4* Kb = (const float4*)K4 + b * NN + kc * 256;   // uniform
        const float* cb = CV + b * NN + kc * 256;                   // uniform
        float t0=-1e30f,t1=-1e30f,t2=-1e30f,t3=-1e30f;
        float t4=-1e30f,t5=-1e30f,t6=-1e30f,t7=-1e30f;
        #pragma unroll 2
        for (int i0 = 0; i0 < 256; i0 += 8) {
            float4 k0 = Kb[i0 + 0]; float4 k1 = Kb[i0 + 1];
            float4 k2 = Kb[i0 + 2]; float4 k3 = Kb[i0 + 3];
            float4 k4 = Kb[i0 + 4]; float4 k5 = Kb[i0 + 5];
            float4 k6 = Kb[i0 + 6]; float4 k7 = Kb[i0 + 7];
            float s0 = fmaf(qv.x,k0.x, fmaf(qv.y,k0.y, fmaf(qv.z,k0.z, qv.w*k0.w))) + cb[i0+0];
            float s1 = fmaf(qv.x,k1.x, fmaf(qv.y,k1.y, fmaf(qv.z,k1.z, qv.w*k1.w))) + cb[i0+1];
            float s2 = fmaf(qv.x,k2.x, fmaf(qv.y,k2.y, fmaf(qv.z,k2.z, qv.w*k2.w))) + cb[i0+2];
            float s3 = fmaf(qv.x,k3.x, fmaf(qv.y,k3.y, fmaf(qv.z,k3.z, qv.w*k3.w))) + cb[i0+3];
            float s4 = fmaf(qv.x,k4.x, fmaf(qv.y,k4.y, fmaf(qv.z,k4.z, qv.w*k4.w))) + cb[i0+4];
            float s5 = fmaf(qv.x,k5.x, fmaf(qv.y,k5.y, fmaf(qv.z,k5.z, qv.w*k5.w))) + cb[i0+5];
            float s6 = fmaf(qv.x,k6.x, fmaf(qv.y,k6.y, fmaf(qv.z,k6.z, qv.w*k6.w))) + cb[i0+6];
            float s7 = fmaf(qv.x,k7.x, fmaf(qv.y,k7.y, fmaf(qv.z,k7.z, qv.w*k7.w))) + cb[i0+7];
            float bm = fmaxf(fmaxf(fmaxf(s0,s1), fmaxf(s2,s3)),
                             fmaxf(fmaxf(s4,s5), fmaxf(s6,s7)));
            if (bm > t0) {
                CE(s0,s1); CE(s2,s3); CE(s4,s5); CE(s6,s7);
                CE(s0,s2); CE(s1,s3); CE(s4,s6); CE(s5,s7);
                CE(s1,s2); CE(s5,s6);
                CE(s0,s4); CE(s1,s5); CE(s2,s6); CE(s3,s7);
                CE(s2,s4); CE(s3,s5);
                CE(s1,s2); CE(s3,s4); CE(s5,s6);
                t0 = fmaxf(t0, s7); t1 = fmaxf(t1, s6); t2 = fmaxf(t2, s5); t3 = fmaxf(t3, s4);
                t4 = fmaxf(t4, s3); t5 = fmaxf(t5, s2); t6 = fmaxf(t6, s1); t7 = fmaxf(t7, s0);
                CE(t0,t4); CE(t1,t5); CE(t2,t6); CE(t3,t7);
                CE(t0,t2); CE(t1,t3); CE(t4,t6); CE(t5,t7);
                CE(t0,t1); CE(t2,t3); CE(t4,t5); CE(t6,t7);
            }
        }
        float* o = T8 + ((size_t)(b * NN + qrow)) * 128 + kc * 8;
        o[0] = t0; o[1] = t1; o[2] = t2; o[3] = t3;
        o[4] = t4; o[5] = t5; o[6] = t6; o[7] = t7;
    }
    __threadfence(); gg.sync();

    // ---- stage 5: merge 128 candidates -> cm/rmap (4096 vblocks) ----
    for (int vb = bid; vb < 4096; vb += GD) {
        int qid = vb * 4 + (tid >> 6);
        int lane = tid & 63;
        float va = T8[(size_t)qid * 128 + lane];
        float vbv = T8[(size_t)qid * 128 + 64 + lane];
        float hi = fmaxf(va, vbv), lo = fminf(va, vbv);
        float sm = 0.0f;
        #pragma unroll
        for (int r = 0; r < 8; ++r) {
            float m = hi;
            int ln = lane;
            #pragma unroll
            for (int off = 32; off >= 1; off >>= 1) {
                float om = __shfl_xor(m, off);
                int ol = __shfl_xor(ln, off);
                if (om > m || (om == m && ol < ln)) { m = om; ln = ol; }
            }
            sm += exp2f(m);
            if (lane == ln) { hi = lo; lo = -1e30f; }
        }
        if (lane == 0) {
            float cmv = sm * 0.125f;
            int b = qid >> 12, hw = qid & 4095;
            float mr = bilin32(mapin, b, hw >> 6, hw & 63);
            float cm = cmv * mr + mr;
            RMAP[qid] = 1.0f / (1.0f + __expf(cm));
            CMAPF[qid] = cm;
            outp[OUT_CM_OFF + qid] = cm;
        }
    }
    __threadfence(); gg.sync();

    // ---- stage 6: conv1x1 (512 vblocks) ----
    {
        float* ws_ = (float*)smem;             // 1024 f
        float* bs  = (float*)(smem + 4096);    // 32 f
        for (int i = tid; i < 1024; i += 256) ws_[i] = w_in[i];
        if (tid < 32) bs[tid] = b_in[tid];
        __syncthreads();
        int gid = bid * 256 + tid;
        int hw = gid & 4095;
        int og = (gid >> 12) & 7;
        int b  = gid >> 15;
        float rm = RMAP[b * NN + hw];
        float acc[4];
        #pragma unroll
        for (int j = 0; j < 4; ++j) acc[j] = bs[og * 4 + j];
        const float* fb = f + (size_t)b * CH * NN + hw;
        for (int i = 0; i < 32; ++i) {
            float v = fb[i * NN] * rm;
            #pragma unroll
            for (int j = 0; j < 4; ++j) acc[j] += ws_[(og * 4 + j) * 32 + i] * v;
        }
        float* xo = XA + (size_t)b * CH * NN + (og * 4) * NN + hw;
        #pragma unroll
        for (int j = 0; j < 4; ++j) xo[j * NN] = acc[j];
    }
    __threadfence(); gg.sync();

    // ---- stages 7-9: 3x3 conv layers (512 vblocks each) ----
    const float* k5in[3]; float* k5out[3];
    k5in[0] = XA; k5out[0] = XB;
    k5in[1] = XB; k5out[1] = XA;
    k5in[2] = XA; k5out[2] = XB;
    for (int L = 0; L < 3; ++L) {
        float (*tile)[324] = (float (*)[324])smem;          // 41472 B
        float* wsm = (float*)(smem + 41472);                // 1152 f
        float* bsm = (float*)(smem + 46080);                // 4 f
        const float* xin = k5in[L];
        float* xout = k5out[L];
        const float* w = w_mid + L * 9216;
        const float* bias = b_mid + L * 32;
        int blk = bid;
        int og = blk & 7;  blk >>= 3;
        int tx = blk & 3;  blk >>= 2;
        int ty = blk & 3;  blk >>= 2;
        int b  = blk;
        for (int i = tid; i < 1152; i += 256) wsm[i] = w[og * 1152 + i];
        if (tid < 4) bsm[tid] = bias[og * 4 + tid];
        int y0 = ty * 16 - 1, x0 = tx * 16 - 1;
        for (int i = tid; i < 32 * 324; i += 256) {
            int c = i / 324, r = i % 324;
            int yy = r / 18, xx = r % 18;
            int gy = y0 + yy, gx = x0 + xx;
            float v = 0.0f;
            if (gy >= 0 && gy < 64 && gx >= 0 && gx < 64)
                v = xin[((size_t)b * CH + c) * NN + gy * 64 + gx];
            tile[c][r] = v;
        }
        __syncthreads();
        int py = tid >> 4, px = tid & 15;
        float acc[4];
        #pragma unroll
        for (int j = 0; j < 4; ++j) acc[j] = bsm[j];
        for (int i = 0; i < 32; ++i) {
            const float* tr = &tile[i][py * 18 + px];
            float v00 = tr[0],  v01 = tr[1],  v02 = tr[2];
            float v10 = tr[18], v11 = tr[19], v12 = tr[20];
            float v20 = tr[36], v21 = tr[37], v22 = tr[38];
            #pragma unroll
            for (int j = 0; j < 4; ++j) {
                const float* wj = &wsm[j * 288 + i * 9];
                acc[j] += v00 * wj[0] + v01 * wj[1] + v02 * wj[2]
                        + v10 * wj[3] + v11 * wj[4] + v12 * wj[5]
                        + v20 * wj[6] + v21 * wj[7] + v22 * wj[8];
            }
        }
        size_t base = (size_t)b * CH * NN + (size_t)(og * 4) * NN
                    + (ty * 16 + py) * 64 + tx * 16 + px;
        #pragma unroll
        for (int j = 0; j < 4; ++j) {
            float r_ = fmaxf(acc[j], 0.0f);
            xout[base + j * NN] = r_;
            if (L == 2) outp[OUT_X_OFF + base + j * NN] = r_;
        }
        __threadfence(); gg.sync();
    }

    // ---- stage 10: final conv 32->1 + cmap (512 vblocks of 32 px) ----
    {
        float* wsm = (float*)smem;             // 288 f
        float* red = (float*)(smem + 1152);    // 256 f
        for (int i = tid; i < 288; i += 256) wsm[i] = w_out[i];
        int pxi = tid & 31, g = tid >> 5;      // 8 groups x 4 ch
        int gid = bid * 32 + pxi;
        int b = gid >> 12, hw = gid & 4095;
        int y = hw >> 6, x = hw & 63;
        __syncthreads();
        float acc = 0.0f;
        int c0 = g * 4;
        for (int i = c0; i < c0 + 4; ++i) {
            const float* xi = XB + ((size_t)b * CH + i) * NN;
            #pragma unroll
            for (int ky = 0; ky < 3; ++ky) {
                int gy = y + ky - 1;
                if (gy < 0 || gy > 63) continue;
                #pragma unroll
                for (int kx = 0; kx < 3; ++kx) {
                    int gx = x + kx - 1;
                    if (gx < 0 || gx > 63) continue;
                    acc += xi[gy * 64 + gx] * wsm[i * 9 + ky * 3 + kx];
                }
            }
        }
        red[tid] = acc;
        __syncthreads();
        if (tid < 32) {
            float a = 0.0f;
            #pragma unroll
            for (int j = 0; j < 8; ++j) a += red[tid + 32 * j];
            a += b_out[0] + CMAPF[gid];
            outp[OUT_O_OFF + gid] = a;
        }
    }
}

// ================= FALLBACK: proven round-11/12 kernel set =================
__global__ __launch_bounds__(512) void fk1_qk(
        const float* __restrict__ fq, const float* __restrict__ fk,
        const float* __restrict__ wq, const float* __restrict__ wk,
        float* __restrict__ Q4, float* __restrict__ K4) {
    __shared__ float wqs[256], wks[256];
    __shared__ float pp[1024];
    __shared__ float red[512][9];
    int tid = threadIdx.x;
    if (tid < 256) { wqs[tid] = wq[tid]; wks[tid] = wk[tid]; }
    __syncthreads();
    if (tid < 64) {
        float coord = (float)(tid + 1);
        float qy[4] = {0,0,0,0}, qx[4] = {0,0,0,0}, ky[4] = {0,0,0,0}, kx[4] = {0,0,0,0};
        for (int c = 0; c < 32; ++c) {
            float e = (2.0f * (float)(c >> 1)) * (1.0f / 32.0f);
            float ang = coord * exp2f(-e * L2_10K);
            float pr = (c & 1) ? cosf(ang) : sinf(ang);
            #pragma unroll
            for (int m = 0; m < 4; ++m) {
                qy[m] += wqs[m * 64 + c] * pr;
                qx[m] += wqs[m * 64 + 32 + c] * pr;
                ky[m] += wks[m * 64 + c] * pr;
                kx[m] += wks[m * 64 + 32 + c] * pr;
            }
        }
        #pragma unroll
        for (int m = 0; m < 4; ++m) {
            pp[0 * 256 + m * 64 + tid] = qy[m];
            pp[1 * 256 + m * 64 + tid] = qx[m];
            pp[2 * 256 + m * 64 + tid] = ky[m];
            pp[3 * 256 + m * 64 + tid] = kx[m];
        }
    }
    int qi = tid & 63, g = tid >> 6;
    int gid = blockIdx.x * 64 + qi;
    int b = gid >> 12, hw = gid & 4095;
    const float* fqb = fq + (size_t)b * CIN * NN + hw;
    const float* fkb = fk + (size_t)b * CIN * NN + hw;
    float aq[4] = {0,0,0,0}, ak[4] = {0,0,0,0};
    int c0 = g * 8;
    #pragma unroll
    for (int c = c0; c < c0 + 8; ++c) {
        float vq = fqb[c * NN];
        float vk = fkb[c * NN];
        #pragma unroll
        for (int m = 0; m < 4; ++m) {
            aq[m] += wqs[m * 64 + c] * vq;
            ak[m] += wks[m * 64 + c] * vk;
        }
    }
    #pragma unroll
    for (int m = 0; m < 4; ++m) { red[tid][m] = aq[m]; red[tid][4 + m] = ak[m]; }
    __syncthreads();
    if (tid < 64) {
        int y = hw >> 6, x = hw & 63;
        float q4[4], k4[4];
        #pragma unroll
        for (int m = 0; m < 4; ++m) {
            float sq = 0.0f, sk = 0.0f;
            #pragma unroll
            for (int j = 0; j < 8; ++j) {
                sq += red[tid + 64 * j][m];
                sk += red[tid + 64 * j][4 + m];
            }
            q4[m] = LOG2E * (sq + pp[0 * 256 + m * 64 + y] + pp[1 * 256 + m * 64 + x]);
            k4[m] = sk + pp[2 * 256 + m * 64 + y] + pp[3 * 256 + m * 64 + x];
        }
        ((float4*)Q4)[gid] = make_float4(q4[0], q4[1], q4[2], q4[3]);
        ((float4*)K4)[gid] = make_float4(k4[0], k4[1], k4[2], k4[3]);
    }
}

__global__ void fk2a(const float* __restrict__ Q4, const float* __restrict__ K4,
                     float* __restrict__ cpsum) {
    int blk = blockIdx.x;
    int kblk = blk & 7;   blk >>= 3;
    int qch  = blk & 31;  blk >>= 5;
    int b    = blk;
    int tid = threadIdx.x;
    const float4* Qg = (const float4*)Q4 + b * NN + qch * 128;
    int k0 = kblk * 512 + tid;
    float4 kva = ((const float4*)K4)[b * NN + k0];
    float4 kvb = ((const float4*)K4)[b * NN + k0 + 256];
    float sa = 0.0f, sb = 0.0f;
    #pragma unroll 8
    for (int i = 0; i < 128; ++i) {
        float4 q = Qg[i];
        float da = fmaf(q.x, kva.x, fmaf(q.y, kva.y, fmaf(q.z, kva.z, q.w * kva.w)));
        float db = fmaf(q.x, kvb.x, fmaf(q.y, kvb.y, fmaf(q.z, kvb.z, q.w * kvb.w)));
        sa += exp2f(da);
        sb += exp2f(db);
    }
    cpsum[(b * NQCH + qch) * NN + k0] = sa;
    cpsum[(b * NQCH + qch) * NN + k0 + 256] = sb;
}

__global__ void fk2b(const float* __restrict__ cpsum, const float* __restrict__ m_k,
                     float* __restrict__ cvals) {
    int gid = blockIdx.x * 256 + threadIdx.x;
    int b = gid >> 12, k = gid & 4095;
    float S = 0.0f;
    #pragma unroll
    for (int j = 0; j < NQCH; ++j) S += cpsum[(b * NQCH + j) * NN + k];
    float mk = bilin32(m_k, b, k >> 6, k & 63);
    cvals[gid] = LOG2E * (mk - 1.0f) - log2f(S);
}

__global__ __launch_bounds__(256) void fk3a(
        const float* __restrict__ Q4, const float* __restrict__ K4,
        const float* __restrict__ cvals, float* __restrict__ t8) {
    int blk = blockIdx.x;
    int kc = blk & 15;  blk >>= 4;
    int g4 = blk & 15;  blk >>= 4;
    int b  = blk;
    int tid = threadIdx.x;
    int wave = tid >> 6, lane = tid & 63;
    int qrow = (g4 * 4 + wave) * 64 + lane;
    float4 qv = ((const float4*)Q4)[b * NN + qrow];
    const float4* Kb = (const float4*)K4 + b * NN + kc * 256;
    const float* cb = cvals + b * NN + kc * 256;
    float t0=-1e30f,t1=-1e30f,t2=-1e30f,t3=-1e30f;
    float t4=-1e30f,t5=-1e30f,t6=-1e30f,t7=-1e30f;
    #pragma unroll 2
    for (int i0 = 0; i0 < 256; i0 += 8) {
        float4 k0 = Kb[i0 + 0]; float4 k1 = Kb[i0 + 1];
        float4 k2 = Kb[i0 + 2]; float4 k3 = Kb[i0 + 3];
        float4 k4 = Kb[i0 + 4]; float4 k5 = Kb[i0 + 5];
        float4 k6 = Kb[i0 + 6]; float4 k7 = Kb[i0 + 7];
        float s0 = fmaf(qv.x,k0.x, fmaf(qv.y,k0.y, fmaf(qv.z,k0.z, qv.w*k0.w))) + cb[i0+0];
        float s1 = fmaf(qv.x,k1.x, fmaf(qv.y,k1.y, fmaf(qv.z,k1.z, qv.w*k1.w))) + cb[i0+1];
        float s2 = fmaf(qv.x,k2.x, fmaf(qv.y,k2.y, fmaf(qv.z,k2.z, qv.w*k2.w))) + cb[i0+2];
        float s3 = fmaf(qv.x,k3.x, fmaf(qv.y,k3.y, fmaf(qv.z,k3.z, qv.w*k3.w))) + cb[i0+3];
        float s4 = fmaf(qv.x,k4.x, fmaf(qv.y,k4.y, fmaf(qv.z,k4.z, qv.w*k4.w))) + cb[i0+4];
        float s5 = fmaf(qv.x,k5.x, fmaf(qv.y,k5.y, fmaf(qv.z,k5.z, qv.w*k5.w))) + cb[i0+5];
        float s6 = fmaf(qv.x,k6.x, fmaf(qv.y,k6.y, fmaf(qv.z,k6.z, qv.w*k6.w))) + cb[i0+6];
        float s7 = fmaf(qv.x,k7.x, fmaf(qv.y,k7.y, fmaf(qv.z,k7.z, qv.w*k7.w))) + cb[i0+7];
        float bm = fmaxf(fmaxf(fmaxf(s0,s1), fmaxf(s2,s3)),
                         fmaxf(fmaxf(s4,s5), fmaxf(s6,s7)));
        if (bm > t0) {
            CE(s0,s1); CE(s2,s3); CE(s4,s5); CE(s6,s7);
            CE(s0,s2); CE(s1,s3); CE(s4,s6); CE(s5,s7);
            CE(s1,s2); CE(s5,s6);
            CE(s0,s4); CE(s1,s5); CE(s2,s6); CE(s3,s7);
            CE(s2,s4); CE(s3,s5);
            CE(s1,s2); CE(s3,s4); CE(s5,s6);
            t0 = fmaxf(t0, s7); t1 = fmaxf(t1, s6); t2 = fmaxf(t2, s5); t3 = fmaxf(t3, s4);
            t4 = fmaxf(t4, s3); t5 = fmaxf(t5, s2); t6 = fmaxf(t6, s1); t7 = fmaxf(t7, s0);
            CE(t0,t4); CE(t1,t5); CE(t2,t6); CE(t3,t7);
            CE(t0,t2); CE(t1,t3); CE(t4,t6); CE(t5,t7);
            CE(t0,t1); CE(t2,t3); CE(t4,t5); CE(t6,t7);
        }
    }
    float* o = t8 + ((size_t)(b * NN + qrow)) * 128 + kc * 8;
    o[0] = t0; o[1] = t1; o[2] = t2; o[3] = t3;
    o[4] = t4; o[5] = t5; o[6] = t6; o[7] = t7;
}

__global__ void fk3b(const float* __restrict__ t8, const float* __restrict__ mapin,
                     float* __restrict__ rmap, float* __restrict__ cmapf,
                     float* __restrict__ outp) {
    int tid = threadIdx.x;
    int qid = blockIdx.x * 4 + (tid >> 6);
    int lane = tid & 63;
    float va = t8[(size_t)qid * 128 + lane];
    float vb = t8[(size_t)qid * 128 + 64 + lane];
    float hi = fmaxf(va, vb), lo = fminf(va, vb);
    float sm = 0.0f;
    #pragma unroll
    for (int r = 0; r < 8; ++r) {
        float m = hi;
        int ln = lane;
        #pragma unroll
        for (int off = 32; off >= 1; off >>= 1) {
            float om = __shfl_xor(m, off);
            int ol = __shfl_xor(ln, off);
            if (om > m || (om == m && ol < ln)) { m = om; ln = ol; }
        }
        sm += exp2f(m);
        if (lane == ln) { hi = lo; lo = -1e30f; }
    }
    if (lane == 0) {
        float cmv = sm * 0.125f;
        int b = qid >> 12, hw = qid & 4095;
        float mr = bilin32(mapin, b, hw >> 6, hw & 63);
        float cm = cmv * mr + mr;
        rmap[qid] = 1.0f / (1.0f + __expf(cm));
        cmapf[qid] = cm;
        outp[OUT_CM_OFF + qid] = cm;
    }
}

__global__ void fk4(const float* __restrict__ f, const float* __restrict__ rmap,
                    const float* __restrict__ w_in, const float* __restrict__ b_in,
                    float* __restrict__ xout) {
    __shared__ float ws_[1024];
    __shared__ float bs[32];
    int tid = threadIdx.x;
    for (int i = tid; i < 1024; i += 256) ws_[i] = w_in[i];
    if (tid < 32) bs[tid] = b_in[tid];
    __syncthreads();
    int gid = blockIdx.x * 256 + tid;
    int hw = gid & 4095;
    int og = (gid >> 12) & 7;
    int b  = gid >> 15;
    float rm = rmap[b * NN + hw];
    float acc[4];
    #pragma unroll
    for (int j = 0; j < 4; ++j) acc[j] = bs[og * 4 + j];
    const float* fb = f + (size_t)b * CH * NN + hw;
    for (int i = 0; i < 32; ++i) {
        float v = fb[i * NN] * rm;
        #pragma unroll
        for (int j = 0; j < 4; ++j) acc[j] += ws_[(og * 4 + j) * 32 + i] * v;
    }
    float* xo = xout + (size_t)b * CH * NN + (og * 4) * NN + hw;
    #pragma unroll
    for (int j = 0; j < 4; ++j) xo[j * NN] = acc[j];
}

__global__ void fk5(const float* __restrict__ xin, const float* __restrict__ w,
                    const float* __restrict__ bias, float* __restrict__ xout,
                    float* __restrict__ outx) {
    __shared__ float tile[32][324];
    __shared__ float wsm[1152];
    __shared__ float bsm[4];
    int blk = blockIdx.x;
    int og = blk & 7;  blk >>= 3;
    int tx = blk & 3;  blk >>= 2;
    int ty = blk & 3;  blk >>= 2;
    int b  = blk;
    int tid = threadIdx.x;
    for (int i = tid; i < 1152; i += 256) wsm[i] = w[og * 1152 + i];
    if (tid < 4) bsm[tid] = bias[og * 4 + tid];
    int y0 = ty * 16 - 1, x0 = tx * 16 - 1;
    for (int i = tid; i < 32 * 324; i += 256) {
        int c = i / 324, r = i % 324;
        int yy = r / 18, xx = r % 18;
        int gy = y0 + yy, gx = x0 + xx;
        float v = 0.0f;
        if (gy >= 0 && gy < 64 && gx >= 0 && gx < 64)
            v = xin[((size_t)b * CH + c) * NN + gy * 64 + gx];
        tile[c][r] = v;
    }
    __syncthreads();
    int py = tid >> 4, px = tid & 15;
    float acc[4];
    #pragma unroll
    for (int j = 0; j < 4; ++j) acc[j] = bsm[j];
    for (int i = 0; i < 32; ++i) {
        const float* tr = &tile[i][py * 18 + px];
        float v00 = tr[0],  v01 = tr[1],  v02 = tr[2];
        float v10 = tr[18], v11 = tr[19], v12 = tr[20];
        float v20 = tr[36], v21 = tr[37], v22 = tr[38];
        #pragma unroll
        for (int j = 0; j < 4; ++j) {
            const float* wj = &wsm[j * 288 + i * 9];
            acc[j] += v00 * wj[0] + v01 * wj[1] + v02 * wj[2]
                    + v10 * wj[3] + v11 * wj[4] + v12 * wj[5]
                    + v20 * wj[6] + v21 * wj[7] + v22 * wj[8];
        }
    }
    size_t base = (size_t)b * CH * NN + (size_t)(og * 4) * NN
                + (ty * 16 + py) * 64 + tx * 16 + px;
    #pragma unroll
    for (int j = 0; j < 4; ++j) {
        float r_ = fmaxf(acc[j], 0.0f);
        xout[base + j * NN] = r_;
        if (outx) outx[base + j * NN] = r_;
    }
}

__global__ void fk6(const float* __restrict__ xin, const float* __restrict__ w_out,
                    const float* __restrict__ b_out, const float* __restrict__ cmapf,
                    float* __restrict__ outp) {
    __shared__ float wsm[288];
    __shared__ float red[256];
    int tid = threadIdx.x;
    for (int i = tid; i < 288; i += 256) wsm[i] = w_out[i];
    int pxi = tid & 63, g = tid >> 6;
    int gid = blockIdx.x * 64 + pxi;
    int b = gid >> 12, hw = gid & 4095;
    int y = hw >> 6, x = hw & 63;
    __syncthreads();
    float acc = 0.0f;
    int c0 = g * 8;
    for (int i = c0; i < c0 + 8; ++i) {
        const float* xi = xin + ((size_t)b * CH + i) * NN;
        #pragma unroll
        for (int ky = 0; ky < 3; ++ky) {
            int gy = y + ky - 1;
            if (gy < 0 || gy > 63) continue;
            #pragma unroll
            for (int kx = 0; kx < 3; ++kx) {
                int gx = x + kx - 1;
                if (gx < 0 || gx > 63) continue;
                acc += xi[gy * 64 + gx] * wsm[i * 9 + ky * 3 + kx];
            }
        }
    }
    red[tid] = acc;
    __syncthreads();
    if (tid < 64) {
        float a = red[tid] + red[tid + 64] + red[tid + 128] + red[tid + 192]
                + b_out[0] + cmapf[gid];
        outp[OUT_O_OFF + gid] = a;
    }
}

extern "C" void kernel_launch(void* const* d_in, const int* in_sizes, int n_in,
                              void* d_out, int out_size, void* d_ws, size_t ws_size,
                              hipStream_t stream) {
    const float* f     = (const float*)d_in[0];
    const float* mapin = (const float*)d_in[1];
    const float* f_q   = (const float*)d_in[2];
    const float* f_k   = (const float*)d_in[3];
    const float* m_k   = (const float*)d_in[4];
    const float* wq    = (const float*)d_in[5];
    const float* wk    = (const float*)d_in[6];
    const float* w_in  = (const float*)d_in[7];
    const float* b_in  = (const float*)d_in[8];
    const float* w_mid = (const float*)d_in[9];
    const float* b_mid = (const float*)d_in[10];
    const float* w_out = (const float*)d_in[11];
    const float* b_out = (const float*)d_in[12];
    float* outp = (float*)d_out;
    float* wsf  = (float*)d_ws;

    void* kargs[] = {
        (void*)&f, (void*)&mapin, (void*)&f_q, (void*)&f_k, (void*)&m_k,
        (void*)&wq, (void*)&wk, (void*)&w_in, (void*)&b_in, (void*)&w_mid,
        (void*)&b_mid, (void*)&w_out, (void*)&b_out, (void*)&outp, (void*)&wsf
    };
    hipError_t cerr = hipLaunchCooperativeKernel((void*)mega, dim3(512), dim3(256),
                                                 kargs, 0, stream);
    if (cerr != hipSuccess) {
        // fallback: proven multi-kernel path (round-11/12 config, 206 us)
        float* Q4    = wsf + Q4_OFF;
        float* K4    = wsf + K4_OFF;
        float* CV    = wsf + CV_OFF;
        float* CPSUM = wsf + CPSUM_OFF;
        float* RMAP  = wsf + RMAP_OFF;
        float* CMAPF = wsf + CMAPF_OFF;
        float* T8    = wsf + T8_OFF;
        float* XA    = wsf + XA_OFF;
        float* XB    = wsf + XB_OFF;
        fk1_qk<<<256, 512, 0, stream>>>(f_q, f_k, wq, wk, Q4, K4);
        fk2a<<<BB * NQCH * 8, 256, 0, stream>>>(Q4, K4, CPSUM);
        fk2b<<<64, 256, 0, stream>>>(CPSUM, m_k, CV);
        fk3a<<<BB * 16 * 16, 256, 0, stream>>>(Q4, K4, CV, T8);
        fk3b<<<BB * NN / 4, 256, 0, stream>>>(T8, mapin, RMAP, CMAPF, outp);
        fk4<<<512, 256, 0, stream>>>(f, RMAP, w_in, b_in, XA);
        fk5<<<512, 256, 0, stream>>>(XA, w_mid + 0 * 9216, b_mid + 0 * 32, XB, (float*)0);
        fk5<<<512, 256, 0, stream>>>(XB, w_mid + 1 * 9216, b_mid + 1 * 32, XA, (float*)0);
        fk5<<<512, 256, 0, stream>>>(XA, w_mid + 2 * 9216, b_mid + 2 * 32, XB, outp + OUT_X_OFF);
        fk6<<<256, 256, 0, stream>>>(XB, w_out, b_out, CMAPF, outp);
    }
}

// Round 15
// 207.395 us; speedup vs baseline: 5.5938x; 5.5938x over previous
//
#include <hip/hip_runtime.h>
#include <hip/hip_bf16.h>
#include <math.h>

// Problem constants
#define BB 4
#define CIN 64
#define CH 32
#define NN 4096
#define NQCH 32
#define LOG2E 1.4426950408889634f
#define L2_10K 13.287712379549449f

// ws layout (floats). End = 2,278,400 floats = 8.69 MiB (ws >= 10.16 MiB proven).
// Temporal aliasing: CPSUM (k2a->k2b) and XA/XB (k4..k6) alias T8's region;
// T8 live only k3a->k3b, written after k2b, dead before k4.
#define Q4_OFF     1024
#define K4_OFF     66560
#define CV_OFF     132096
#define RMAP_OFF   148480
#define CMAPF_OFF  164864
#define T8_OFF     181248      // 2097152 (16 chunks x 8 per query)
#define CPSUM_OFF  181248      // aliases T8 head; dead before k3a
#define XA_OFF     181248      // aliases T8; written k4 (after k3b)
#define XB_OFF     705536      // aliases T8; written k5

// out layout (f32): x | out | corrected_map
#define OUT_X_OFF   0
#define OUT_O_OFF   524288
#define OUT_CM_OFF  540672

#define CE(x, y) { float ce_lo = fminf(x, y); y = fmaxf(x, y); x = ce_lo; }

// Batcher odd-even mergesort, 8 elems ascending (19 CE) — verified r11-13
#define SORT8(a0,a1,a2,a3,a4,a5,a6,a7) \
    CE(a0,a1); CE(a2,a3); CE(a4,a5); CE(a6,a7); \
    CE(a0,a2); CE(a1,a3); CE(a4,a6); CE(a5,a7); \
    CE(a1,a2); CE(a5,a6); \
    CE(a0,a4); CE(a1,a5); CE(a2,a6); CE(a3,a7); \
    CE(a2,a4); CE(a3,a5); \
    CE(a1,a2); CE(a3,a4); CE(a5,a6);

// bitonic -> ascending sort of 8 (12 CE) — verified r11-13
#define BITONIC8(a0,a1,a2,a3,a4,a5,a6,a7) \
    CE(a0,a4); CE(a1,a5); CE(a2,a6); CE(a3,a7); \
    CE(a0,a2); CE(a1,a3); CE(a4,a6); CE(a5,a7); \
    CE(a0,a1); CE(a2,a3); CE(a4,a5); CE(a6,a7);

__device__ __forceinline__ float bilin32(const float* src, int b, int y, int x) {
    float sy = 0.5f * y - 0.25f;
    float sx = 0.5f * x - 0.25f;
    float fy0 = floorf(sy), fx0 = floorf(sx);
    int y0 = (int)fy0, x0 = (int)fx0;
    float fy = sy - fy0, fx = sx - fx0;
    int y0c = min(max(y0, 0), 31), y1c = min(max(y0 + 1, 0), 31);
    int x0c = min(max(x0, 0), 31), x1c = min(max(x0 + 1, 0), 31);
    const float* p = src + b * 1024;
    float v00 = p[y0c * 32 + x0c], v01 = p[y0c * 32 + x1c];
    float v10 = p[y1c * 32 + x0c], v11 = p[y1c * 32 + x1c];
    float v0 = v00 + fx * (v01 - v00);
    float v1 = v10 + fx * (v11 - v10);
    return v0 + fy * (v1 - v0);
}

// K1: Q/K projections, pos table fused in-block, channel-split 8x8.
// 512-thread blocks, 64 queries/block, grid = B*N/64 = 256. (round-12 proven)
__global__ __launch_bounds__(512) void k1_qk(
        const float* __restrict__ fq, const float* __restrict__ fk,
        const float* __restrict__ wq, const float* __restrict__ wk,
        float* __restrict__ Q4, float* __restrict__ K4) {
    __shared__ float wqs[256], wks[256];
    __shared__ float pp[1024];
    __shared__ float red[512][9];
    int tid = threadIdx.x;
    if (tid < 256) { wqs[tid] = wq[tid]; wks[tid] = wk[tid]; }
    __syncthreads();
    if (tid < 64) {
        float coord = (float)(tid + 1);
        float qy[4] = {0,0,0,0}, qx[4] = {0,0,0,0}, ky[4] = {0,0,0,0}, kx[4] = {0,0,0,0};
        for (int c = 0; c < 32; ++c) {
            float e = (2.0f * (float)(c >> 1)) * (1.0f / 32.0f);
            float ang = coord * exp2f(-e * L2_10K);
            float pr = (c & 1) ? cosf(ang) : sinf(ang);
            #pragma unroll
            for (int m = 0; m < 4; ++m) {
                qy[m] += wqs[m * 64 + c] * pr;
                qx[m] += wqs[m * 64 + 32 + c] * pr;
                ky[m] += wks[m * 64 + c] * pr;
                kx[m] += wks[m * 64 + 32 + c] * pr;
            }
        }
        #pragma unroll
        for (int m = 0; m < 4; ++m) {
            pp[0 * 256 + m * 64 + tid] = qy[m];
            pp[1 * 256 + m * 64 + tid] = qx[m];
            pp[2 * 256 + m * 64 + tid] = ky[m];
            pp[3 * 256 + m * 64 + tid] = kx[m];
        }
    }
    int qi = tid & 63, g = tid >> 6;
    int gid = blockIdx.x * 64 + qi;
    int b = gid >> 12, hw = gid & 4095;
    const float* fqb = fq + (size_t)b * CIN * NN + hw;
    const float* fkb = fk + (size_t)b * CIN * NN + hw;
    float aq[4] = {0,0,0,0}, ak[4] = {0,0,0,0};
    int c0 = g * 8;
    #pragma unroll
    for (int c = c0; c < c0 + 8; ++c) {
        float vq = fqb[c * NN];
        float vk = fkb[c * NN];
        #pragma unroll
        for (int m = 0; m < 4; ++m) {
            aq[m] += wqs[m * 64 + c] * vq;
            ak[m] += wks[m * 64 + c] * vk;
        }
    }
    #pragma unroll
    for (int m = 0; m < 4; ++m) { red[tid][m] = aq[m]; red[tid][4 + m] = ak[m]; }
    __syncthreads();
    if (tid < 64) {
        int y = hw >> 6, x = hw & 63;
        float q4[4], k4[4];
        #pragma unroll
        for (int m = 0; m < 4; ++m) {
            float sq = 0.0f, sk = 0.0f;
            #pragma unroll
            for (int j = 0; j < 8; ++j) {
                sq += red[tid + 64 * j][m];
                sk += red[tid + 64 * j][4 + m];
            }
            q4[m] = LOG2E * (sq + pp[0 * 256 + m * 64 + y] + pp[1 * 256 + m * 64 + x]);
            k4[m] = sk + pp[2 * 256 + m * 64 + y] + pp[3 * 256 + m * 64 + x];
        }
        ((float4*)Q4)[gid] = make_float4(q4[0], q4[1], q4[2], q4[3]);
        ((float4*)K4)[gid] = make_float4(k4[0], k4[1], k4[2], k4[3]);
    }
}

// K2a: per-(b, q-chunk of 128) column sum of 2^(q'.k), 2 keys/thread.
// grid = B*NQCH*8 = 1024. (round-12 proven)
__global__ void k2a_colstats(const float* __restrict__ Q4, const float* __restrict__ K4,
                             float* __restrict__ cpsum) {
    int blk = blockIdx.x;
    int kblk = blk & 7;   blk >>= 3;
    int qch  = blk & 31;  blk >>= 5;
    int b    = blk;
    int tid = threadIdx.x;
    const float4* Qg = (const float4*)Q4 + b * NN + qch * 128;  // uniform base
    int k0 = kblk * 512 + tid;
    float4 kva = ((const float4*)K4)[b * NN + k0];
    float4 kvb = ((const float4*)K4)[b * NN + k0 + 256];
    float sa = 0.0f, sb = 0.0f;
    #pragma unroll 8
    for (int i = 0; i < 128; ++i) {
        float4 q = Qg[i];
        float da = fmaf(q.x, kva.x, fmaf(q.y, kva.y, fmaf(q.z, kva.z, q.w * kva.w)));
        float db = fmaf(q.x, kvb.x, fmaf(q.y, kvb.y, fmaf(q.z, kvb.z, q.w * kvb.w)));
        sa += exp2f(da);
        sb += exp2f(db);
    }
    cpsum[(b * NQCH + qch) * NN + k0] = sa;
    cpsum[(b * NQCH + qch) * NN + k0 + 256] = sb;
}

// K2b: merge chunk sums -> c'[b][k] = LOG2E*(m_k_r - 1) - log2(colsum)
__global__ void k2b_cmerge(const float* __restrict__ cpsum,
                           const float* __restrict__ m_k, float* __restrict__ cvals) {
    int gid = blockIdx.x * 256 + threadIdx.x;
    int b = gid >> 12, k = gid & 4095;
    float S = 0.0f;
    #pragma unroll
    for (int j = 0; j < NQCH; ++j) S += cpsum[(b * NQCH + j) * NN + k];
    float mk = bilin32(m_k, b, k >> 6, k & 63);
    cvals[gid] = LOG2E * (mk - 1.0f) - log2f(S);
}

// K3a v6: lane-per-query chunk scan, BATCH-16 selection.
// Keys + c via uniform scalar loads (SGPR broadcast). Per batch: 16 dots,
// 15-fmax guard; on fire: SORT8 x2 (38 CE) + union-top8 (8 fmax + BITONIC8)
// + merge-into-t (8 fmax + BITONIC8) = 78 CE / 16 keys = 4.9 CE/key
// (was 6.4 with batch-8). grid = B*16*16 = 1024 x 256.
__global__ __launch_bounds__(256) void k3a_scan(
        const float* __restrict__ Q4, const float* __restrict__ K4,
        const float* __restrict__ cvals, float* __restrict__ t8) {
    int blk = blockIdx.x;
    int kc = blk & 15;  blk >>= 4;
    int g4 = blk & 15;  blk >>= 4;
    int b  = blk;
    int tid = threadIdx.x;
    int wave = tid >> 6, lane = tid & 63;
    int qrow = (g4 * 4 + wave) * 64 + lane;
    float4 qv = ((const float4*)Q4)[b * NN + qrow];
    const float4* Kb = (const float4*)K4 + b * NN + kc * 256;   // uniform base
    const float* cb = cvals + b * NN + kc * 256;                // uniform base

    float t0=-1e30f,t1=-1e30f,t2=-1e30f,t3=-1e30f;
    float t4=-1e30f,t5=-1e30f,t6=-1e30f,t7=-1e30f;   // ascending; t0 = 8th

    for (int i0 = 0; i0 < 256; i0 += 16) {
        // c values packed: 4 x s_load_dwordx4 (uniform)
        float4 cA = *(const float4*)(cb + i0);
        float4 cB = *(const float4*)(cb + i0 + 4);
        float4 cC = *(const float4*)(cb + i0 + 8);
        float4 cD = *(const float4*)(cb + i0 + 12);
        float4 k0 = Kb[i0 + 0];  float4 k1 = Kb[i0 + 1];
        float4 k2 = Kb[i0 + 2];  float4 k3 = Kb[i0 + 3];
        float4 k4 = Kb[i0 + 4];  float4 k5 = Kb[i0 + 5];
        float4 k6 = Kb[i0 + 6];  float4 k7 = Kb[i0 + 7];
        float s0 = fmaf(qv.x,k0.x, fmaf(qv.y,k0.y, fmaf(qv.z,k0.z, qv.w*k0.w))) + cA.x;
        float s1 = fmaf(qv.x,k1.x, fmaf(qv.y,k1.y, fmaf(qv.z,k1.z, qv.w*k1.w))) + cA.y;
        float s2 = fmaf(qv.x,k2.x, fmaf(qv.y,k2.y, fmaf(qv.z,k2.z, qv.w*k2.w))) + cA.z;
        float s3 = fmaf(qv.x,k3.x, fmaf(qv.y,k3.y, fmaf(qv.z,k3.z, qv.w*k3.w))) + cA.w;
        float s4 = fmaf(qv.x,k4.x, fmaf(qv.y,k4.y, fmaf(qv.z,k4.z, qv.w*k4.w))) + cB.x;
        float s5 = fmaf(qv.x,k5.x, fmaf(qv.y,k5.y, fmaf(qv.z,k5.z, qv.w*k5.w))) + cB.y;
        float s6 = fmaf(qv.x,k6.x, fmaf(qv.y,k6.y, fmaf(qv.z,k6.z, qv.w*k6.w))) + cB.z;
        float s7 = fmaf(qv.x,k7.x, fmaf(qv.y,k7.y, fmaf(qv.z,k7.z, qv.w*k7.w))) + cB.w;
        float4 k8 = Kb[i0 + 8];  float4 k9 = Kb[i0 + 9];
        float4 kA = Kb[i0 + 10]; float4 kB = Kb[i0 + 11];
        float4 kC = Kb[i0 + 12]; float4 kD = Kb[i0 + 13];
        float4 kE = Kb[i0 + 14]; float4 kF = Kb[i0 + 15];
        float s8 = fmaf(qv.x,k8.x, fmaf(qv.y,k8.y, fmaf(qv.z,k8.z, qv.w*k8.w))) + cC.x;
        float s9 = fmaf(qv.x,k9.x, fmaf(qv.y,k9.y, fmaf(qv.z,k9.z, qv.w*k9.w))) + cC.y;
        float sA = fmaf(qv.x,kA.x, fmaf(qv.y,kA.y, fmaf(qv.z,kA.z, qv.w*kA.w))) + cC.z;
        float sB = fmaf(qv.x,kB.x, fmaf(qv.y,kB.y, fmaf(qv.z,kB.z, qv.w*kB.w))) + cC.w;
        float sC = fmaf(qv.x,kC.x, fmaf(qv.y,kC.y, fmaf(qv.z,kC.z, qv.w*kC.w))) + cD.x;
        float sD = fmaf(qv.x,kD.x, fmaf(qv.y,kD.y, fmaf(qv.z,kD.z, qv.w*kD.w))) + cD.y;
        float sE = fmaf(qv.x,kE.x, fmaf(qv.y,kE.y, fmaf(qv.z,kE.z, qv.w*kE.w))) + cD.z;
        float sF = fmaf(qv.x,kF.x, fmaf(qv.y,kF.y, fmaf(qv.z,kF.z, qv.w*kF.w))) + cD.w;
        float bm = fmaxf(
            fmaxf(fmaxf(fmaxf(s0,s1), fmaxf(s2,s3)), fmaxf(fmaxf(s4,s5), fmaxf(s6,s7))),
            fmaxf(fmaxf(fmaxf(s8,s9), fmaxf(sA,sB)), fmaxf(fmaxf(sC,sD), fmaxf(sE,sF))));
        if (bm > t0) {
            SORT8(s0,s1,s2,s3,s4,s5,s6,s7);       // ascending
            SORT8(s8,s9,sA,sB,sC,sD,sE,sF);       // ascending
            // union top-8 of the two sorted-8s (bitonic) -> sort
            float u0 = fmaxf(s0, sF), u1 = fmaxf(s1, sE);
            float u2 = fmaxf(s2, sD), u3 = fmaxf(s3, sC);
            float u4 = fmaxf(s4, sB), u5 = fmaxf(s5, sA);
            float u6 = fmaxf(s6, s9), u7 = fmaxf(s7, s8);
            BITONIC8(u0,u1,u2,u3,u4,u5,u6,u7);    // ascending
            // merge into running top-8
            t0 = fmaxf(t0, u7); t1 = fmaxf(t1, u6); t2 = fmaxf(t2, u5); t3 = fmaxf(t3, u4);
            t4 = fmaxf(t4, u3); t5 = fmaxf(t5, u2); t6 = fmaxf(t6, u1); t7 = fmaxf(t7, u0);
            BITONIC8(t0,t1,t2,t3,t4,t5,t6,t7);    // ascending
        }
    }
    float* o = t8 + ((size_t)(b * NN + qrow)) * 128 + kc * 8;
    o[0] = t0; o[1] = t1; o[2] = t2; o[3] = t3;
    o[4] = t4; o[5] = t5; o[6] = t6; o[7] = t7;
}

// K3b: merge 16 chunk-top8s (128 candidates) -> global top-8 -> cm/rmap.
__global__ void k3b_merge(const float* __restrict__ t8, const float* __restrict__ mapin,
                          float* __restrict__ rmap, float* __restrict__ cmapf,
                          float* __restrict__ outp) {
    int tid = threadIdx.x;
    int qid = blockIdx.x * 4 + (tid >> 6);
    int lane = tid & 63;
    float va = t8[(size_t)qid * 128 + lane];
    float vb = t8[(size_t)qid * 128 + 64 + lane];
    float hi = fmaxf(va, vb), lo = fminf(va, vb);
    float sm = 0.0f;
    #pragma unroll
    for (int r = 0; r < 8; ++r) {
        float m = hi;
        int ln = lane;
        #pragma unroll
        for (int off = 32; off >= 1; off >>= 1) {
            float om = __shfl_xor(m, off);
            int ol = __shfl_xor(ln, off);
            if (om > m || (om == m && ol < ln)) { m = om; ln = ol; }
        }
        sm += exp2f(m);
        if (lane == ln) { hi = lo; lo = -1e30f; }
    }
    if (lane == 0) {
        float cmv = sm * 0.125f;
        int b = qid >> 12, hw = qid & 4095;
        float mr = bilin32(mapin, b, hw >> 6, hw & 63);
        float cm = cmv * mr + mr;
        rmap[qid] = 1.0f / (1.0f + __expf(cm));
        cmapf[qid] = cm;
        outp[OUT_CM_OFF + qid] = cm;
    }
}

// K4: x1 = conv1x1(rmap*f, w_in) + b_in. og-split 8 -> grid 512
__global__ void k4_conv1(const float* __restrict__ f, const float* __restrict__ rmap,
                         const float* __restrict__ w_in, const float* __restrict__ b_in,
                         float* __restrict__ xout) {
    __shared__ float ws_[1024];
    __shared__ float bs[32];
    int tid = threadIdx.x;
    for (int i = tid; i < 1024; i += 256) ws_[i] = w_in[i];
    if (tid < 32) bs[tid] = b_in[tid];
    __syncthreads();
    int gid = blockIdx.x * 256 + tid;
    int hw = gid & 4095;
    int og = (gid >> 12) & 7;
    int b  = gid >> 15;
    float rm = rmap[b * NN + hw];
    float acc[4];
    #pragma unroll
    for (int j = 0; j < 4; ++j) acc[j] = bs[og * 4 + j];
    const float* fb = f + (size_t)b * CH * NN + hw;
    for (int i = 0; i < 32; ++i) {
        float v = fb[i * NN] * rm;
        #pragma unroll
        for (int j = 0; j < 4; ++j) acc[j] += ws_[(og * 4 + j) * 32 + i] * v;
    }
    float* xo = xout + (size_t)b * CH * NN + (og * 4) * NN + hw;
    #pragma unroll
    for (int j = 0; j < 4; ++j) xo[j * NN] = acc[j];
}

// K5: 3x3 conv 32->32 (+bias, relu). og-split 8 -> grid 512
__global__ void k5_conv3(const float* __restrict__ xin, const float* __restrict__ w,
                         const float* __restrict__ bias, float* __restrict__ xout,
                         float* __restrict__ outx) {
    __shared__ float tile[32][324];
    __shared__ float wsm[1152];
    __shared__ float bsm[4];
    int blk = blockIdx.x;
    int og = blk & 7;  blk >>= 3;
    int tx = blk & 3;  blk >>= 2;
    int ty = blk & 3;  blk >>= 2;
    int b  = blk;
    int tid = threadIdx.x;
    for (int i = tid; i < 1152; i += 256) wsm[i] = w[og * 1152 + i];
    if (tid < 4) bsm[tid] = bias[og * 4 + tid];
    int y0 = ty * 16 - 1, x0 = tx * 16 - 1;
    for (int i = tid; i < 32 * 324; i += 256) {
        int c = i / 324, r = i % 324;
        int yy = r / 18, xx = r % 18;
        int gy = y0 + yy, gx = x0 + xx;
        float v = 0.0f;
        if (gy >= 0 && gy < 64 && gx >= 0 && gx < 64)
            v = xin[((size_t)b * CH + c) * NN + gy * 64 + gx];
        tile[c][r] = v;
    }
    __syncthreads();
    int py = tid >> 4, px = tid & 15;
    float acc[4];
    #pragma unroll
    for (int j = 0; j < 4; ++j) acc[j] = bsm[j];
    for (int i = 0; i < 32; ++i) {
        const float* tr = &tile[i][py * 18 + px];
        float v00 = tr[0],  v01 = tr[1],  v02 = tr[2];
        float v10 = tr[18], v11 = tr[19], v12 = tr[20];
        float v20 = tr[36], v21 = tr[37], v22 = tr[38];
        #pragma unroll
        for (int j = 0; j < 4; ++j) {
            const float* wj = &wsm[j * 288 + i * 9];
            acc[j] += v00 * wj[0] + v01 * wj[1] + v02 * wj[2]
                    + v10 * wj[3] + v11 * wj[4] + v12 * wj[5]
                    + v20 * wj[6] + v21 * wj[7] + v22 * wj[8];
        }
    }
    size_t base = (size_t)b * CH * NN + (size_t)(og * 4) * NN
                + (ty * 16 + py) * 64 + tx * 16 + px;
    #pragma unroll
    for (int j = 0; j < 4; ++j) {
        float r_ = fmaxf(acc[j], 0.0f);
        xout[base + j * NN] = r_;
        if (outx) outx[base + j * NN] = r_;
    }
}

// K6: final 3x3 conv 32->1 + b_out + corrected_map. channel-split 4x8, grid 256
__global__ void k6_convout(const float* __restrict__ xin, const float* __restrict__ w_out,
                           const float* __restrict__ b_out, const float* __restrict__ cmapf,
                           float* __restrict__ outp) {
    __shared__ float wsm[288];
    __shared__ float red[256];
    int tid = threadIdx.x;
    for (int i = tid; i < 288; i += 256) wsm[i] = w_out[i];
    int pxi = tid & 63, g = tid >> 6;
    int gid = blockIdx.x * 64 + pxi;
    int b = gid >> 12, hw = gid & 4095;
    int y = hw >> 6, x = hw & 63;
    __syncthreads();
    float acc = 0.0f;
    int c0 = g * 8;
    for (int i = c0; i < c0 + 8; ++i) {
        const float* xi = xin + ((size_t)b * CH + i) * NN;
        #pragma unroll
        for (int ky = 0; ky < 3; ++ky) {
            int gy = y + ky - 1;
            if (gy < 0 || gy > 63) continue;
            #pragma unroll
            for (int kx = 0; kx < 3; ++kx) {
                int gx = x + kx - 1;
                if (gx < 0 || gx > 63) continue;
                acc += xi[gy * 64 + gx] * wsm[i * 9 + ky * 3 + kx];
            }
        }
    }
    red[tid] = acc;
    __syncthreads();
    if (tid < 64) {
        float a = red[tid] + red[tid + 64] + red[tid + 128] + red[tid + 192]
                + b_out[0] + cmapf[gid];
        outp[OUT_O_OFF + gid] = a;
    }
}

extern "C" void kernel_launch(void* const* d_in, const int* in_sizes, int n_in,
                              void* d_out, int out_size, void* d_ws, size_t ws_size,
                              hipStream_t stream) {
    const float* f     = (const float*)d_in[0];
    const float* mapin = (const float*)d_in[1];
    const float* f_q   = (const float*)d_in[2];
    const float* f_k   = (const float*)d_in[3];
    const float* m_k   = (const float*)d_in[4];
    const float* wq    = (const float*)d_in[5];
    const float* wk    = (const float*)d_in[6];
    const float* w_in  = (const float*)d_in[7];
    const float* b_in  = (const float*)d_in[8];
    const float* w_mid = (const float*)d_in[9];
    const float* b_mid = (const float*)d_in[10];
    const float* w_out = (const float*)d_in[11];
    const float* b_out = (const float*)d_in[12];
    float* outp = (float*)d_out;
    float* ws = (float*)d_ws;

    float* Q4    = ws + Q4_OFF;
    float* K4    = ws + K4_OFF;
    float* CV    = ws + CV_OFF;
    float* CPSUM = ws + CPSUM_OFF;
    float* RMAP  = ws + RMAP_OFF;
    float* CMAPF = ws + CMAPF_OFF;
    float* T8    = ws + T8_OFF;
    float* XA    = ws + XA_OFF;
    float* XB    = ws + XB_OFF;

    k1_qk<<<256, 512, 0, stream>>>(f_q, f_k, wq, wk, Q4, K4);
    k2a_colstats<<<BB * NQCH * 8, 256, 0, stream>>>(Q4, K4, CPSUM);
    k2b_cmerge<<<64, 256, 0, stream>>>(CPSUM, m_k, CV);
    k3a_scan<<<BB * 16 * 16, 256, 0, stream>>>(Q4, K4, CV, T8);
    k3b_merge<<<BB * NN / 4, 256, 0, stream>>>(T8, mapin, RMAP, CMAPF, outp);
    k4_conv1<<<512, 256, 0, stream>>>(f, RMAP, w_in, b_in, XA);
    k5_conv3<<<512, 256, 0, stream>>>(XA, w_mid + 0 * 9216, b_mid + 0 * 32, XB, (float*)0);
    k5_conv3<<<512, 256, 0, stream>>>(XB, w_mid + 1 * 9216, b_mid + 1 * 32, XA, (float*)0);
    k5_conv3<<<512, 256, 0, stream>>>(XA, w_mid + 2 * 9216, b_mid + 2 * 32, XB, outp + OUT_X_OFF);
    k6_convout<<<256, 256, 0, stream>>>(XB, w_out, b_out, CMAPF, outp);
}

// Round 16
// 202.235 us; speedup vs baseline: 5.7365x; 1.0255x over previous
//
#include <hip/hip_runtime.h>
#include <hip/hip_bf16.h>
#include <math.h>

// Problem constants
#define BB 4
#define CIN 64
#define CH 32
#define NN 4096
#define NQCH 32
#define LOG2E 1.4426950408889634f
#define L2_10K 13.287712379549449f

// ws layout (floats). ws_size PROVEN ~268 MB (harness fillBuffer = 2.685e8 B).
// NO ALIASING — every buffer has its own region. End = 5,948,416 floats = 23.8 MiB.
#define Q4_OFF     1024        // 65536  (Q pre-scaled by LOG2E)
#define K4_OFF     66560       // 65536
#define CV_OFF     132096      // 16384  (c' in log2 domain)
#define RMAP_OFF   148480      // 16384
#define CMAPF_OFF  164864      // 16384
#define CPSUM_OFF  181248      // 524288
#define T8_OFF     705536      // 4194304 (32 chunks x 8 per query)
#define XA_OFF     4899840     // 524288
#define XB_OFF     5424128     // 524288

// out layout (f32): x | out | corrected_map
#define OUT_X_OFF   0
#define OUT_O_OFF   524288
#define OUT_CM_OFF  540672

#define CE(x, y) { float ce_lo = fminf(x, y); y = fmaxf(x, y); x = ce_lo; }
// descending compare-exchange (x keeps max)
#define CED(x, y) { float ce_hi = fmaxf(x, y); y = fminf(x, y); x = ce_hi; }

// Batcher odd-even mergesort, 8 elems ascending (19 CE) — verified r11-15
#define SORT8(a0,a1,a2,a3,a4,a5,a6,a7) \
    CE(a0,a1); CE(a2,a3); CE(a4,a5); CE(a6,a7); \
    CE(a0,a2); CE(a1,a3); CE(a4,a6); CE(a5,a7); \
    CE(a1,a2); CE(a5,a6); \
    CE(a0,a4); CE(a1,a5); CE(a2,a6); CE(a3,a7); \
    CE(a2,a4); CE(a3,a5); \
    CE(a1,a2); CE(a3,a4); CE(a5,a6);

// bitonic -> ascending sort of 8 (12 CE) — verified r11-15
#define BITONIC8(a0,a1,a2,a3,a4,a5,a6,a7) \
    CE(a0,a4); CE(a1,a5); CE(a2,a6); CE(a3,a7); \
    CE(a0,a2); CE(a1,a3); CE(a4,a6); CE(a5,a7); \
    CE(a0,a1); CE(a2,a3); CE(a4,a5); CE(a6,a7);

__device__ __forceinline__ float bilin32(const float* src, int b, int y, int x) {
    float sy = 0.5f * y - 0.25f;
    float sx = 0.5f * x - 0.25f;
    float fy0 = floorf(sy), fx0 = floorf(sx);
    int y0 = (int)fy0, x0 = (int)fx0;
    float fy = sy - fy0, fx = sx - fx0;
    int y0c = min(max(y0, 0), 31), y1c = min(max(y0 + 1, 0), 31);
    int x0c = min(max(x0, 0), 31), x1c = min(max(x0 + 1, 0), 31);
    const float* p = src + b * 1024;
    float v00 = p[y0c * 32 + x0c], v01 = p[y0c * 32 + x1c];
    float v10 = p[y1c * 32 + x0c], v11 = p[y1c * 32 + x1c];
    float v0 = v00 + fx * (v01 - v00);
    float v1 = v10 + fx * (v11 - v10);
    return v0 + fy * (v1 - v0);
}

// K1: Q/K projections, pos table fused in-block, channel-split 8x8.
// 512-thread blocks, 64 queries/block, grid = B*N/64 = 256. (r12/r15 proven)
__global__ __launch_bounds__(512) void k1_qk(
        const float* __restrict__ fq, const float* __restrict__ fk,
        const float* __restrict__ wq, const float* __restrict__ wk,
        float* __restrict__ Q4, float* __restrict__ K4) {
    __shared__ float wqs[256], wks[256];
    __shared__ float pp[1024];
    __shared__ float red[512][9];
    int tid = threadIdx.x;
    if (tid < 256) { wqs[tid] = wq[tid]; wks[tid] = wk[tid]; }
    __syncthreads();
    if (tid < 64) {
        float coord = (float)(tid + 1);
        float qy[4] = {0,0,0,0}, qx[4] = {0,0,0,0}, ky[4] = {0,0,0,0}, kx[4] = {0,0,0,0};
        for (int c = 0; c < 32; ++c) {
            float e = (2.0f * (float)(c >> 1)) * (1.0f / 32.0f);
            float ang = coord * exp2f(-e * L2_10K);
            float pr = (c & 1) ? cosf(ang) : sinf(ang);
            #pragma unroll
            for (int m = 0; m < 4; ++m) {
                qy[m] += wqs[m * 64 + c] * pr;
                qx[m] += wqs[m * 64 + 32 + c] * pr;
                ky[m] += wks[m * 64 + c] * pr;
                kx[m] += wks[m * 64 + 32 + c] * pr;
            }
        }
        #pragma unroll
        for (int m = 0; m < 4; ++m) {
            pp[0 * 256 + m * 64 + tid] = qy[m];
            pp[1 * 256 + m * 64 + tid] = qx[m];
            pp[2 * 256 + m * 64 + tid] = ky[m];
            pp[3 * 256 + m * 64 + tid] = kx[m];
        }
    }
    int qi = tid & 63, g = tid >> 6;
    int gid = blockIdx.x * 64 + qi;
    int b = gid >> 12, hw = gid & 4095;
    const float* fqb = fq + (size_t)b * CIN * NN + hw;
    const float* fkb = fk + (size_t)b * CIN * NN + hw;
    float aq[4] = {0,0,0,0}, ak[4] = {0,0,0,0};
    int c0 = g * 8;
    #pragma unroll
    for (int c = c0; c < c0 + 8; ++c) {
        float vq = fqb[c * NN];
        float vk = fkb[c * NN];
        #pragma unroll
        for (int m = 0; m < 4; ++m) {
            aq[m] += wqs[m * 64 + c] * vq;
            ak[m] += wks[m * 64 + c] * vk;
        }
    }
    #pragma unroll
    for (int m = 0; m < 4; ++m) { red[tid][m] = aq[m]; red[tid][4 + m] = ak[m]; }
    __syncthreads();
    if (tid < 64) {
        int y = hw >> 6, x = hw & 63;
        float q4[4], k4[4];
        #pragma unroll
        for (int m = 0; m < 4; ++m) {
            float sq = 0.0f, sk = 0.0f;
            #pragma unroll
            for (int j = 0; j < 8; ++j) {
                sq += red[tid + 64 * j][m];
                sk += red[tid + 64 * j][4 + m];
            }
            q4[m] = LOG2E * (sq + pp[0 * 256 + m * 64 + y] + pp[1 * 256 + m * 64 + x]);
            k4[m] = sk + pp[2 * 256 + m * 64 + y] + pp[3 * 256 + m * 64 + x];
        }
        ((float4*)Q4)[gid] = make_float4(q4[0], q4[1], q4[2], q4[3]);
        ((float4*)K4)[gid] = make_float4(k4[0], k4[1], k4[2], k4[3]);
    }
}

// K2a: per-(b, q-chunk of 128) column sum of 2^(q'.k), 2 keys/thread.
// grid = B*NQCH*8 = 1024. (r12/r15 proven)
__global__ void k2a_colstats(const float* __restrict__ Q4, const float* __restrict__ K4,
                             float* __restrict__ cpsum) {
    int blk = blockIdx.x;
    int kblk = blk & 7;   blk >>= 3;
    int qch  = blk & 31;  blk >>= 5;
    int b    = blk;
    int tid = threadIdx.x;
    const float4* Qg = (const float4*)Q4 + b * NN + qch * 128;  // uniform base
    int k0 = kblk * 512 + tid;
    float4 kva = ((const float4*)K4)[b * NN + k0];
    float4 kvb = ((const float4*)K4)[b * NN + k0 + 256];
    float sa = 0.0f, sb = 0.0f;
    #pragma unroll 8
    for (int i = 0; i < 128; ++i) {
        float4 q = Qg[i];
        float da = fmaf(q.x, kva.x, fmaf(q.y, kva.y, fmaf(q.z, kva.z, q.w * kva.w)));
        float db = fmaf(q.x, kvb.x, fmaf(q.y, kvb.y, fmaf(q.z, kvb.z, q.w * kvb.w)));
        sa += exp2f(da);
        sb += exp2f(db);
    }
    cpsum[(b * NQCH + qch) * NN + k0] = sa;
    cpsum[(b * NQCH + qch) * NN + k0 + 256] = sb;
}

// K2b: merge chunk sums -> c'[b][k] = LOG2E*(m_k_r - 1) - log2(colsum)
__global__ void k2b_cmerge(const float* __restrict__ cpsum,
                           const float* __restrict__ m_k, float* __restrict__ cvals) {
    int gid = blockIdx.x * 256 + threadIdx.x;
    int b = gid >> 12, k = gid & 4095;
    float S = 0.0f;
    #pragma unroll
    for (int j = 0; j < NQCH; ++j) S += cpsum[(b * NQCH + j) * NN + k];
    float mk = bilin32(m_k, b, k >> 6, k & 63);
    cvals[gid] = LOG2E * (mk - 1.0f) - log2f(S);
}

// K3a v7: lane-per-query chunk scan, 32 chunks of 128 keys, batch-16 body.
// grid = B*16*32 = 2048 blocks x 256 thr = 8192 waves = 8/SIMD (2x r15).
// Keys + c via uniform scalar loads (SGPR broadcast).
__global__ __launch_bounds__(256) void k3a_scan(
        const float* __restrict__ Q4, const float* __restrict__ K4,
        const float* __restrict__ cvals, float* __restrict__ t8) {
    int blk = blockIdx.x;
    int kc = blk & 31;  blk >>= 5;
    int g4 = blk & 15;  blk >>= 4;
    int b  = blk;
    int tid = threadIdx.x;
    int wave = tid >> 6, lane = tid & 63;
    int qrow = (g4 * 4 + wave) * 64 + lane;
    float4 qv = ((const float4*)Q4)[b * NN + qrow];
    const float4* Kb = (const float4*)K4 + b * NN + kc * 128;   // uniform base
    const float* cb = cvals + b * NN + kc * 128;                // uniform base

    float t0=-1e30f,t1=-1e30f,t2=-1e30f,t3=-1e30f;
    float t4=-1e30f,t5=-1e30f,t6=-1e30f,t7=-1e30f;   // ascending; t0 = 8th

    for (int i0 = 0; i0 < 128; i0 += 16) {
        float4 cA = *(const float4*)(cb + i0);
        float4 cB = *(const float4*)(cb + i0 + 4);
        float4 cC = *(const float4*)(cb + i0 + 8);
        float4 cD = *(const float4*)(cb + i0 + 12);
        float4 k0 = Kb[i0 + 0];  float4 k1 = Kb[i0 + 1];
        float4 k2 = Kb[i0 + 2];  float4 k3 = Kb[i0 + 3];
        float4 k4 = Kb[i0 + 4];  float4 k5 = Kb[i0 + 5];
        float4 k6 = Kb[i0 + 6];  float4 k7 = Kb[i0 + 7];
        float s0 = fmaf(qv.x,k0.x, fmaf(qv.y,k0.y, fmaf(qv.z,k0.z, qv.w*k0.w))) + cA.x;
        float s1 = fmaf(qv.x,k1.x, fmaf(qv.y,k1.y, fmaf(qv.z,k1.z, qv.w*k1.w))) + cA.y;
        float s2 = fmaf(qv.x,k2.x, fmaf(qv.y,k2.y, fmaf(qv.z,k2.z, qv.w*k2.w))) + cA.z;
        float s3 = fmaf(qv.x,k3.x, fmaf(qv.y,k3.y, fmaf(qv.z,k3.z, qv.w*k3.w))) + cA.w;
        float s4 = fmaf(qv.x,k4.x, fmaf(qv.y,k4.y, fmaf(qv.z,k4.z, qv.w*k4.w))) + cB.x;
        float s5 = fmaf(qv.x,k5.x, fmaf(qv.y,k5.y, fmaf(qv.z,k5.z, qv.w*k5.w))) + cB.y;
        float s6 = fmaf(qv.x,k6.x, fmaf(qv.y,k6.y, fmaf(qv.z,k6.z, qv.w*k6.w))) + cB.z;
        float s7 = fmaf(qv.x,k7.x, fmaf(qv.y,k7.y, fmaf(qv.z,k7.z, qv.w*k7.w))) + cB.w;
        float4 k8 = Kb[i0 + 8];  float4 k9 = Kb[i0 + 9];
        float4 kA = Kb[i0 + 10]; float4 kB = Kb[i0 + 11];
        float4 kC = Kb[i0 + 12]; float4 kD = Kb[i0 + 13];
        float4 kE = Kb[i0 + 14]; float4 kF = Kb[i0 + 15];
        float s8 = fmaf(qv.x,k8.x, fmaf(qv.y,k8.y, fmaf(qv.z,k8.z, qv.w*k8.w))) + cC.x;
        float s9 = fmaf(qv.x,k9.x, fmaf(qv.y,k9.y, fmaf(qv.z,k9.z, qv.w*k9.w))) + cC.y;
        float sA = fmaf(qv.x,kA.x, fmaf(qv.y,kA.y, fmaf(qv.z,kA.z, qv.w*kA.w))) + cC.z;
        float sB = fmaf(qv.x,kB.x, fmaf(qv.y,kB.y, fmaf(qv.z,kB.z, qv.w*kB.w))) + cC.w;
        float sC = fmaf(qv.x,kC.x, fmaf(qv.y,kC.y, fmaf(qv.z,kC.z, qv.w*kC.w))) + cD.x;
        float sD = fmaf(qv.x,kD.x, fmaf(qv.y,kD.y, fmaf(qv.z,kD.z, qv.w*kD.w))) + cD.y;
        float sE = fmaf(qv.x,kE.x, fmaf(qv.y,kE.y, fmaf(qv.z,kE.z, qv.w*kE.w))) + cD.z;
        float sF = fmaf(qv.x,kF.x, fmaf(qv.y,kF.y, fmaf(qv.z,kF.z, qv.w*kF.w))) + cD.w;
        float bm = fmaxf(
            fmaxf(fmaxf(fmaxf(s0,s1), fmaxf(s2,s3)), fmaxf(fmaxf(s4,s5), fmaxf(s6,s7))),
            fmaxf(fmaxf(fmaxf(s8,s9), fmaxf(sA,sB)), fmaxf(fmaxf(sC,sD), fmaxf(sE,sF))));
        if (bm > t0) {
            SORT8(s0,s1,s2,s3,s4,s5,s6,s7);       // ascending
            SORT8(s8,s9,sA,sB,sC,sD,sE,sF);       // ascending
            float u0 = fmaxf(s0, sF), u1 = fmaxf(s1, sE);
            float u2 = fmaxf(s2, sD), u3 = fmaxf(s3, sC);
            float u4 = fmaxf(s4, sB), u5 = fmaxf(s5, sA);
            float u6 = fmaxf(s6, s9), u7 = fmaxf(s7, s8);
            BITONIC8(u0,u1,u2,u3,u4,u5,u6,u7);    // ascending
            t0 = fmaxf(t0, u7); t1 = fmaxf(t1, u6); t2 = fmaxf(t2, u5); t3 = fmaxf(t3, u4);
            t4 = fmaxf(t4, u3); t5 = fmaxf(t5, u2); t6 = fmaxf(t6, u1); t7 = fmaxf(t7, u0);
            BITONIC8(t0,t1,t2,t3,t4,t5,t6,t7);    // ascending
        }
    }
    float* o = t8 + ((size_t)(b * NN + qrow)) * 256 + kc * 8;
    o[0] = t0; o[1] = t1; o[2] = t2; o[3] = t3;
    o[4] = t4; o[5] = t5; o[6] = t6; o[7] = t7;
}

// K3b: merge 32 chunk-top8s (256 candidates) -> global top-8 -> cm/rmap.
// Lane holds 4 candidates sorted DESC (a>=b>=c>=d); argmax-pop over a.
__global__ void k3b_merge(const float* __restrict__ t8, const float* __restrict__ mapin,
                          float* __restrict__ rmap, float* __restrict__ cmapf,
                          float* __restrict__ outp) {
    int tid = threadIdx.x;
    int qid = blockIdx.x * 4 + (tid >> 6);
    int lane = tid & 63;
    const float* p = t8 + (size_t)qid * 256;
    float a = p[lane], bq = p[lane + 64], c = p[lane + 128], d = p[lane + 192];
    // sort descending (5-CE network): a >= bq >= c >= d
    CED(a, c); CED(bq, d); CED(a, bq); CED(c, d); CED(bq, c);
    float sm = 0.0f;
    #pragma unroll
    for (int r = 0; r < 8; ++r) {
        float m = a;
        int ln = lane;
        #pragma unroll
        for (int off = 32; off >= 1; off >>= 1) {
            float om = __shfl_xor(m, off);
            int ol = __shfl_xor(ln, off);
            if (om > m || (om == m && ol < ln)) { m = om; ln = ol; }
        }
        sm += exp2f(m);
        if (lane == ln) { a = bq; bq = c; c = d; d = -1e30f; }
    }
    if (lane == 0) {
        float cmv = sm * 0.125f;
        int b = qid >> 12, hw = qid & 4095;
        float mr = bilin32(mapin, b, hw >> 6, hw & 63);
        float cm = cmv * mr + mr;
        rmap[qid] = 1.0f / (1.0f + __expf(cm));
        cmapf[qid] = cm;
        outp[OUT_CM_OFF + qid] = cm;
    }
}

// K4: x1 = conv1x1(rmap*f, w_in) + b_in. og-split 8 -> grid 512
__global__ void k4_conv1(const float* __restrict__ f, const float* __restrict__ rmap,
                         const float* __restrict__ w_in, const float* __restrict__ b_in,
                         float* __restrict__ xout) {
    __shared__ float ws_[1024];
    __shared__ float bs[32];
    int tid = threadIdx.x;
    for (int i = tid; i < 1024; i += 256) ws_[i] = w_in[i];
    if (tid < 32) bs[tid] = b_in[tid];
    __syncthreads();
    int gid = blockIdx.x * 256 + tid;
    int hw = gid & 4095;
    int og = (gid >> 12) & 7;
    int b  = gid >> 15;
    float rm = rmap[b * NN + hw];
    float acc[4];
    #pragma unroll
    for (int j = 0; j < 4; ++j) acc[j] = bs[og * 4 + j];
    const float* fb = f + (size_t)b * CH * NN + hw;
    for (int i = 0; i < 32; ++i) {
        float v = fb[i * NN] * rm;
        #pragma unroll
        for (int j = 0; j < 4; ++j) acc[j] += ws_[(og * 4 + j) * 32 + i] * v;
    }
    float* xo = xout + (size_t)b * CH * NN + (og * 4) * NN + hw;
    #pragma unroll
    for (int j = 0; j < 4; ++j) xo[j * NN] = acc[j];
}

// K5: 3x3 conv 32->32 (+bias, relu). og-split 8 -> grid 512
__global__ void k5_conv3(const float* __restrict__ xin, const float* __restrict__ w,
                         const float* __restrict__ bias, float* __restrict__ xout,
                         float* __restrict__ outx) {
    __shared__ float tile[32][324];
    __shared__ float wsm[1152];
    __shared__ float bsm[4];
    int blk = blockIdx.x;
    int og = blk & 7;  blk >>= 3;
    int tx = blk & 3;  blk >>= 2;
    int ty = blk & 3;  blk >>= 2;
    int b  = blk;
    int tid = threadIdx.x;
    for (int i = tid; i < 1152; i += 256) wsm[i] = w[og * 1152 + i];
    if (tid < 4) bsm[tid] = bias[og * 4 + tid];
    int y0 = ty * 16 - 1, x0 = tx * 16 - 1;
    for (int i = tid; i < 32 * 324; i += 256) {
        int c = i / 324, r = i % 324;
        int yy = r / 18, xx = r % 18;
        int gy = y0 + yy, gx = x0 + xx;
        float v = 0.0f;
        if (gy >= 0 && gy < 64 && gx >= 0 && gx < 64)
            v = xin[((size_t)b * CH + c) * NN + gy * 64 + gx];
        tile[c][r] = v;
    }
    __syncthreads();
    int py = tid >> 4, px = tid & 15;
    float acc[4];
    #pragma unroll
    for (int j = 0; j < 4; ++j) acc[j] = bsm[j];
    for (int i = 0; i < 32; ++i) {
        const float* tr = &tile[i][py * 18 + px];
        float v00 = tr[0],  v01 = tr[1],  v02 = tr[2];
        float v10 = tr[18], v11 = tr[19], v12 = tr[20];
        float v20 = tr[36], v21 = tr[37], v22 = tr[38];
        #pragma unroll
        for (int j = 0; j < 4; ++j) {
            const float* wj = &wsm[j * 288 + i * 9];
            acc[j] += v00 * wj[0] + v01 * wj[1] + v02 * wj[2]
                    + v10 * wj[3] + v11 * wj[4] + v12 * wj[5]
                    + v20 * wj[6] + v21 * wj[7] + v22 * wj[8];
        }
    }
    size_t base = (size_t)b * CH * NN + (size_t)(og * 4) * NN
                + (ty * 16 + py) * 64 + tx * 16 + px;
    #pragma unroll
    for (int j = 0; j < 4; ++j) {
        float r_ = fmaxf(acc[j], 0.0f);
        xout[base + j * NN] = r_;
        if (outx) outx[base + j * NN] = r_;
    }
}

// K6: final 3x3 conv 32->1 + b_out + corrected_map. channel-split 4x8, grid 256
__global__ void k6_convout(const float* __restrict__ xin, const float* __restrict__ w_out,
                           const float* __restrict__ b_out, const float* __restrict__ cmapf,
                           float* __restrict__ outp) {
    __shared__ float wsm[288];
    __shared__ float red[256];
    int tid = threadIdx.x;
    for (int i = tid; i < 288; i += 256) wsm[i] = w_out[i];
    int pxi = tid & 63, g = tid >> 6;
    int gid = blockIdx.x * 64 + pxi;
    int b = gid >> 12, hw = gid & 4095;
    int y = hw >> 6, x = hw & 63;
    __syncthreads();
    float acc = 0.0f;
    int c0 = g * 8;
    for (int i = c0; i < c0 + 8; ++i) {
        const float* xi = xin + ((size_t)b * CH + i) * NN;
        #pragma unroll
        for (int ky = 0; ky < 3; ++ky) {
            int gy = y + ky - 1;
            if (gy < 0 || gy > 63) continue;
            #pragma unroll
            for (int kx = 0; kx < 3; ++kx) {
                int gx = x + kx - 1;
                if (gx < 0 || gx > 63) continue;
                acc += xi[gy * 64 + gx] * wsm[i * 9 + ky * 3 + kx];
            }
        }
    }
    red[tid] = acc;
    __syncthreads();
    if (tid < 64) {
        float a = red[tid] + red[tid + 64] + red[tid + 128] + red[tid + 192]
                + b_out[0] + cmapf[gid];
        outp[OUT_O_OFF + gid] = a;
    }
}

extern "C" void kernel_launch(void* const* d_in, const int* in_sizes, int n_in,
                              void* d_out, int out_size, void* d_ws, size_t ws_size,
                              hipStream_t stream) {
    const float* f     = (const float*)d_in[0];
    const float* mapin = (const float*)d_in[1];
    const float* f_q   = (const float*)d_in[2];
    const float* f_k   = (const float*)d_in[3];
    const float* m_k   = (const float*)d_in[4];
    const float* wq    = (const float*)d_in[5];
    const float* wk    = (const float*)d_in[6];
    const float* w_in  = (const float*)d_in[7];
    const float* b_in  = (const float*)d_in[8];
    const float* w_mid = (const float*)d_in[9];
    const float* b_mid = (const float*)d_in[10];
    const float* w_out = (const float*)d_in[11];
    const float* b_out = (const float*)d_in[12];
    float* outp = (float*)d_out;
    float* ws = (float*)d_ws;

    float* Q4    = ws + Q4_OFF;
    float* K4    = ws + K4_OFF;
    float* CV    = ws + CV_OFF;
    float* CPSUM = ws + CPSUM_OFF;
    float* RMAP  = ws + RMAP_OFF;
    float* CMAPF = ws + CMAPF_OFF;
    float* T8    = ws + T8_OFF;
    float* XA    = ws + XA_OFF;
    float* XB    = ws + XB_OFF;

    k1_qk<<<256, 512, 0, stream>>>(f_q, f_k, wq, wk, Q4, K4);
    k2a_colstats<<<BB * NQCH * 8, 256, 0, stream>>>(Q4, K4, CPSUM);
    k2b_cmerge<<<64, 256, 0, stream>>>(CPSUM, m_k, CV);
    k3a_scan<<<BB * 16 * 32, 256, 0, stream>>>(Q4, K4, CV, T8);
    k3b_merge<<<BB * NN / 4, 256, 0, stream>>>(T8, mapin, RMAP, CMAPF, outp);
    k4_conv1<<<512, 256, 0, stream>>>(f, RMAP, w_in, b_in, XA);
    k5_conv3<<<512, 256, 0, stream>>>(XA, w_mid + 0 * 9216, b_mid + 0 * 32, XB, (float*)0);
    k5_conv3<<<512, 256, 0, stream>>>(XB, w_mid + 1 * 9216, b_mid + 1 * 32, XA, (float*)0);
    k5_conv3<<<512, 256, 0, stream>>>(XA, w_mid + 2 * 9216, b_mid + 2 * 32, XB, outp + OUT_X_OFF);
    k6_convout<<<256, 256, 0, stream>>>(XB, w_out, b_out, CMAPF, outp);
}

// Round 17
// 196.266 us; speedup vs baseline: 5.9110x; 1.0304x over previous
//
#include <hip/hip_runtime.h>
#include <hip/hip_bf16.h>
#include <math.h>

// Problem constants
#define BB 4
#define CIN 64
#define CH 32
#define NN 4096
#define NQCH 32
#define LOG2E 1.4426950408889634f
#define L2_10K 13.287712379549449f

// ws layout (floats). ws_size PROVEN ~268 MB. NO aliasing. End = 6,456,320 f = 25.8 MiB.
#define Q4_OFF     1024        // 65536  (Q pre-scaled by LOG2E)
#define K4_OFF     66560       // 65536
#define RMAP_OFF   132096      // 16384
#define CMAPF_OFF  148480      // 16384
#define CPSUM_OFF  164864      // 524288
#define T8_OFF     689152      // 4194304 (32 chunks x 8 per query)
#define G_OFF      4883456     // 524288  (conv1x1(f), no bias, no rmap)
#define XA_OFF     5407744     // 524288
#define XB_OFF     5932032     // 524288

// out layout (f32): x | out | corrected_map
#define OUT_X_OFF   0
#define OUT_O_OFF   524288
#define OUT_CM_OFF  540672

#define CE(x, y) { float ce_lo = fminf(x, y); y = fmaxf(x, y); x = ce_lo; }
#define CED(x, y) { float ce_hi = fmaxf(x, y); y = fminf(x, y); x = ce_hi; }

// Batcher odd-even mergesort, 8 elems ascending (19 CE) — verified r11-16
#define SORT8(a0,a1,a2,a3,a4,a5,a6,a7) \
    CE(a0,a1); CE(a2,a3); CE(a4,a5); CE(a6,a7); \
    CE(a0,a2); CE(a1,a3); CE(a4,a6); CE(a5,a7); \
    CE(a1,a2); CE(a5,a6); \
    CE(a0,a4); CE(a1,a5); CE(a2,a6); CE(a3,a7); \
    CE(a2,a4); CE(a3,a5); \
    CE(a1,a2); CE(a3,a4); CE(a5,a6);

// bitonic -> ascending sort of 8 (12 CE) — verified r11-16
#define BITONIC8(a0,a1,a2,a3,a4,a5,a6,a7) \
    CE(a0,a4); CE(a1,a5); CE(a2,a6); CE(a3,a7); \
    CE(a0,a2); CE(a1,a3); CE(a4,a6); CE(a5,a7); \
    CE(a0,a1); CE(a2,a3); CE(a4,a5); CE(a6,a7);

__device__ __forceinline__ float bilin32(const float* src, int b, int y, int x) {
    float sy = 0.5f * y - 0.25f;
    float sx = 0.5f * x - 0.25f;
    float fy0 = floorf(sy), fx0 = floorf(sx);
    int y0 = (int)fy0, x0 = (int)fx0;
    float fy = sy - fy0, fx = sx - fx0;
    int y0c = min(max(y0, 0), 31), y1c = min(max(y0 + 1, 0), 31);
    int x0c = min(max(x0, 0), 31), x1c = min(max(x0 + 1, 0), 31);
    const float* p = src + b * 1024;
    float v00 = p[y0c * 32 + x0c], v01 = p[y0c * 32 + x1c];
    float v10 = p[y1c * 32 + x0c], v11 = p[y1c * 32 + x1c];
    float v0 = v00 + fx * (v01 - v00);
    float v1 = v10 + fx * (v11 - v10);
    return v0 + fy * (v1 - v0);
}

// K1G: heterogeneous merge. Blocks 0..255: Q/K projection (r12-proven body).
// Blocks 256..511: G = conv1x1(f) WITHOUT bias/rmap (pointwise identity:
// conv1x1(rmap*f)+b = rmap*conv1x1(f)+b, applied later in k5a tile load).
__global__ __launch_bounds__(512) void k1g(
        const float* __restrict__ fq, const float* __restrict__ fk,
        const float* __restrict__ wq, const float* __restrict__ wk,
        const float* __restrict__ f, const float* __restrict__ w_in,
        float* __restrict__ Q4, float* __restrict__ K4, float* __restrict__ G) {
    __shared__ float wqs[256], wks[256];
    __shared__ float pp[1024];
    __shared__ float red[512][9];
    int tid = threadIdx.x;
    if (blockIdx.x < 256) {
        // ---- Q/K projection ----
        if (tid < 256) { wqs[tid] = wq[tid]; wks[tid] = wk[tid]; }
        __syncthreads();
        if (tid < 64) {
            float coord = (float)(tid + 1);
            float qy[4] = {0,0,0,0}, qx[4] = {0,0,0,0}, ky[4] = {0,0,0,0}, kx[4] = {0,0,0,0};
            for (int c = 0; c < 32; ++c) {
                float e = (2.0f * (float)(c >> 1)) * (1.0f / 32.0f);
                float ang = coord * exp2f(-e * L2_10K);
                float pr = (c & 1) ? cosf(ang) : sinf(ang);
                #pragma unroll
                for (int m = 0; m < 4; ++m) {
                    qy[m] += wqs[m * 64 + c] * pr;
                    qx[m] += wqs[m * 64 + 32 + c] * pr;
                    ky[m] += wks[m * 64 + c] * pr;
                    kx[m] += wks[m * 64 + 32 + c] * pr;
                }
            }
            #pragma unroll
            for (int m = 0; m < 4; ++m) {
                pp[0 * 256 + m * 64 + tid] = qy[m];
                pp[1 * 256 + m * 64 + tid] = qx[m];
                pp[2 * 256 + m * 64 + tid] = ky[m];
                pp[3 * 256 + m * 64 + tid] = kx[m];
            }
        }
        int qi = tid & 63, g = tid >> 6;
        int gid = blockIdx.x * 64 + qi;
        int b = gid >> 12, hw = gid & 4095;
        const float* fqb = fq + (size_t)b * CIN * NN + hw;
        const float* fkb = fk + (size_t)b * CIN * NN + hw;
        float aq[4] = {0,0,0,0}, ak[4] = {0,0,0,0};
        int c0 = g * 8;
        #pragma unroll
        for (int c = c0; c < c0 + 8; ++c) {
            float vq = fqb[c * NN];
            float vk = fkb[c * NN];
            #pragma unroll
            for (int m = 0; m < 4; ++m) {
                aq[m] += wqs[m * 64 + c] * vq;
                ak[m] += wks[m * 64 + c] * vk;
            }
        }
        #pragma unroll
        for (int m = 0; m < 4; ++m) { red[tid][m] = aq[m]; red[tid][4 + m] = ak[m]; }
        __syncthreads();
        if (tid < 64) {
            int y = hw >> 6, x = hw & 63;
            float q4[4], k4[4];
            #pragma unroll
            for (int m = 0; m < 4; ++m) {
                float sq = 0.0f, sk = 0.0f;
                #pragma unroll
                for (int j = 0; j < 8; ++j) {
                    sq += red[tid + 64 * j][m];
                    sk += red[tid + 64 * j][4 + m];
                }
                q4[m] = LOG2E * (sq + pp[0 * 256 + m * 64 + y] + pp[1 * 256 + m * 64 + x]);
                k4[m] = sk + pp[2 * 256 + m * 64 + y] + pp[3 * 256 + m * 64 + x];
            }
            ((float4*)Q4)[gid] = make_float4(q4[0], q4[1], q4[2], q4[3]);
            ((float4*)K4)[gid] = make_float4(k4[0], k4[1], k4[2], k4[3]);
        }
    } else {
        // ---- G = conv1x1(f), no bias ----
        if (tid < 1024) { /* wqs+wks+pp reuse as weight store */ }
        float* ws_ = pp;   // 1024 floats
        for (int i = tid; i < 1024; i += 512) ws_[i] = w_in[i];
        __syncthreads();
        int gid = (blockIdx.x - 256) * 512 + tid;   // b(2) og(3) hw(12)
        int hw = gid & 4095;
        int og = (gid >> 12) & 7;
        int b  = gid >> 15;
        float acc[4] = {0.0f, 0.0f, 0.0f, 0.0f};
        const float* fb = f + (size_t)b * CH * NN + hw;
        for (int i = 0; i < 32; ++i) {
            float v = fb[i * NN];
            #pragma unroll
            for (int j = 0; j < 4; ++j) acc[j] += ws_[(og * 4 + j) * 32 + i] * v;
        }
        float* go = G + (size_t)b * CH * NN + (og * 4) * NN + hw;
        #pragma unroll
        for (int j = 0; j < 4; ++j) go[j * NN] = acc[j];
    }
}

// K2a: per-(b, q-chunk of 128) column sum of 2^(q'.k), 2 keys/thread.
// grid = B*NQCH*8 = 1024. (r12-r16 proven)
__global__ void k2a_colstats(const float* __restrict__ Q4, const float* __restrict__ K4,
                             float* __restrict__ cpsum) {
    int blk = blockIdx.x;
    int kblk = blk & 7;   blk >>= 3;
    int qch  = blk & 31;  blk >>= 5;
    int b    = blk;
    int tid = threadIdx.x;
    const float4* Qg = (const float4*)Q4 + b * NN + qch * 128;  // uniform base
    int k0 = kblk * 512 + tid;
    float4 kva = ((const float4*)K4)[b * NN + k0];
    float4 kvb = ((const float4*)K4)[b * NN + k0 + 256];
    float sa = 0.0f, sb = 0.0f;
    #pragma unroll 8
    for (int i = 0; i < 128; ++i) {
        float4 q = Qg[i];
        float da = fmaf(q.x, kva.x, fmaf(q.y, kva.y, fmaf(q.z, kva.z, q.w * kva.w)));
        float db = fmaf(q.x, kvb.x, fmaf(q.y, kvb.y, fmaf(q.z, kvb.z, q.w * kvb.w)));
        sa += exp2f(da);
        sb += exp2f(db);
    }
    cpsum[(b * NQCH + qch) * NN + k0] = sa;
    cpsum[(b * NQCH + qch) * NN + k0 + 256] = sb;
}

// K3a v8: k2b FUSED — block computes c' for its 128 keys into LDS (from CPSUM
// + m_k), then runs the verified batch-16 scan (keys via uniform scalar loads,
// c' via uniform LDS broadcast). grid = B*16*32 = 2048 x 256 (8 waves/SIMD).
__global__ __launch_bounds__(256) void k3a_scan(
        const float* __restrict__ Q4, const float* __restrict__ K4,
        const float* __restrict__ cpsum, const float* __restrict__ m_k,
        float* __restrict__ t8) {
    __shared__ float cvs[128];
    int blk = blockIdx.x;
    int kc = blk & 31;  blk >>= 5;
    int g4 = blk & 15;  blk >>= 4;
    int b  = blk;
    int tid = threadIdx.x;
    if (tid < 128) {
        int k = kc * 128 + tid;
        float S = 0.0f;
        #pragma unroll
        for (int j = 0; j < NQCH; ++j) S += cpsum[(b * NQCH + j) * NN + k];
        float mk = bilin32(m_k, b, k >> 6, k & 63);
        cvs[tid] = LOG2E * (mk - 1.0f) - log2f(S);
    }
    __syncthreads();

    int wave = tid >> 6, lane = tid & 63;
    int qrow = (g4 * 4 + wave) * 64 + lane;
    float4 qv = ((const float4*)Q4)[b * NN + qrow];
    const float4* Kb = (const float4*)K4 + b * NN + kc * 128;   // uniform base

    float t0=-1e30f,t1=-1e30f,t2=-1e30f,t3=-1e30f;
    float t4=-1e30f,t5=-1e30f,t6=-1e30f,t7=-1e30f;   // ascending; t0 = 8th

    for (int i0 = 0; i0 < 128; i0 += 16) {
        float4 cA = *(const float4*)(cvs + i0);
        float4 cB = *(const float4*)(cvs + i0 + 4);
        float4 cC = *(const float4*)(cvs + i0 + 8);
        float4 cD = *(const float4*)(cvs + i0 + 12);
        float4 k0 = Kb[i0 + 0];  float4 k1 = Kb[i0 + 1];
        float4 k2 = Kb[i0 + 2];  float4 k3 = Kb[i0 + 3];
        float4 k4 = Kb[i0 + 4];  float4 k5 = Kb[i0 + 5];
        float4 k6 = Kb[i0 + 6];  float4 k7 = Kb[i0 + 7];
        float s0 = fmaf(qv.x,k0.x, fmaf(qv.y,k0.y, fmaf(qv.z,k0.z, qv.w*k0.w))) + cA.x;
        float s1 = fmaf(qv.x,k1.x, fmaf(qv.y,k1.y, fmaf(qv.z,k1.z, qv.w*k1.w))) + cA.y;
        float s2 = fmaf(qv.x,k2.x, fmaf(qv.y,k2.y, fmaf(qv.z,k2.z, qv.w*k2.w))) + cA.z;
        float s3 = fmaf(qv.x,k3.x, fmaf(qv.y,k3.y, fmaf(qv.z,k3.z, qv.w*k3.w))) + cA.w;
        float s4 = fmaf(qv.x,k4.x, fmaf(qv.y,k4.y, fmaf(qv.z,k4.z, qv.w*k4.w))) + cB.x;
        float s5 = fmaf(qv.x,k5.x, fmaf(qv.y,k5.y, fmaf(qv.z,k5.z, qv.w*k5.w))) + cB.y;
        float s6 = fmaf(qv.x,k6.x, fmaf(qv.y,k6.y, fmaf(qv.z,k6.z, qv.w*k6.w))) + cB.z;
        float s7 = fmaf(qv.x,k7.x, fmaf(qv.y,k7.y, fmaf(qv.z,k7.z, qv.w*k7.w))) + cB.w;
        float4 k8 = Kb[i0 + 8];  float4 k9 = Kb[i0 + 9];
        float4 kA = Kb[i0 + 10]; float4 kB = Kb[i0 + 11];
        float4 kC = Kb[i0 + 12]; float4 kD = Kb[i0 + 13];
        float4 kE = Kb[i0 + 14]; float4 kF = Kb[i0 + 15];
        float s8 = fmaf(qv.x,k8.x, fmaf(qv.y,k8.y, fmaf(qv.z,k8.z, qv.w*k8.w))) + cC.x;
        float s9 = fmaf(qv.x,k9.x, fmaf(qv.y,k9.y, fmaf(qv.z,k9.z, qv.w*k9.w))) + cC.y;
        float sA = fmaf(qv.x,kA.x, fmaf(qv.y,kA.y, fmaf(qv.z,kA.z, qv.w*kA.w))) + cC.z;
        float sB = fmaf(qv.x,kB.x, fmaf(qv.y,kB.y, fmaf(qv.z,kB.z, qv.w*kB.w))) + cC.w;
        float sC = fmaf(qv.x,kC.x, fmaf(qv.y,kC.y, fmaf(qv.z,kC.z, qv.w*kC.w))) + cD.x;
        float sD = fmaf(qv.x,kD.x, fmaf(qv.y,kD.y, fmaf(qv.z,kD.z, qv.w*kD.w))) + cD.y;
        float sE = fmaf(qv.x,kE.x, fmaf(qv.y,kE.y, fmaf(qv.z,kE.z, qv.w*kE.w))) + cD.z;
        float sF = fmaf(qv.x,kF.x, fmaf(qv.y,kF.y, fmaf(qv.z,kF.z, qv.w*kF.w))) + cD.w;
        float bm = fmaxf(
            fmaxf(fmaxf(fmaxf(s0,s1), fmaxf(s2,s3)), fmaxf(fmaxf(s4,s5), fmaxf(s6,s7))),
            fmaxf(fmaxf(fmaxf(s8,s9), fmaxf(sA,sB)), fmaxf(fmaxf(sC,sD), fmaxf(sE,sF))));
        if (bm > t0) {
            SORT8(s0,s1,s2,s3,s4,s5,s6,s7);
            SORT8(s8,s9,sA,sB,sC,sD,sE,sF);
            float u0 = fmaxf(s0, sF), u1 = fmaxf(s1, sE);
            float u2 = fmaxf(s2, sD), u3 = fmaxf(s3, sC);
            float u4 = fmaxf(s4, sB), u5 = fmaxf(s5, sA);
            float u6 = fmaxf(s6, s9), u7 = fmaxf(s7, s8);
            BITONIC8(u0,u1,u2,u3,u4,u5,u6,u7);
            t0 = fmaxf(t0, u7); t1 = fmaxf(t1, u6); t2 = fmaxf(t2, u5); t3 = fmaxf(t3, u4);
            t4 = fmaxf(t4, u3); t5 = fmaxf(t5, u2); t6 = fmaxf(t6, u1); t7 = fmaxf(t7, u0);
            BITONIC8(t0,t1,t2,t3,t4,t5,t6,t7);
        }
    }
    float* o = t8 + ((size_t)(b * NN + qrow)) * 256 + kc * 8;
    o[0] = t0; o[1] = t1; o[2] = t2; o[3] = t3;
    o[4] = t4; o[5] = t5; o[6] = t6; o[7] = t7;
}

// K3b: merge 32 chunk-top8s (256 candidates) -> global top-8 -> cm/rmap.
// (r16 proven)
__global__ void k3b_merge(const float* __restrict__ t8, const float* __restrict__ mapin,
                          float* __restrict__ rmap, float* __restrict__ cmapf,
                          float* __restrict__ outp) {
    int tid = threadIdx.x;
    int qid = blockIdx.x * 4 + (tid >> 6);
    int lane = tid & 63;
    const float* p = t8 + (size_t)qid * 256;
    float a = p[lane], bq = p[lane + 64], c = p[lane + 128], d = p[lane + 192];
    CED(a, c); CED(bq, d); CED(a, bq); CED(c, d); CED(bq, c);   // desc: a>=bq>=c>=d
    float sm = 0.0f;
    #pragma unroll
    for (int r = 0; r < 8; ++r) {
        float m = a;
        int ln = lane;
        #pragma unroll
        for (int off = 32; off >= 1; off >>= 1) {
            float om = __shfl_xor(m, off);
            int ol = __shfl_xor(ln, off);
            if (om > m || (om == m && ol < ln)) { m = om; ln = ol; }
        }
        sm += exp2f(m);
        if (lane == ln) { a = bq; bq = c; c = d; d = -1e30f; }
    }
    if (lane == 0) {
        float cmv = sm * 0.125f;
        int b = qid >> 12, hw = qid & 4095;
        float mr = bilin32(mapin, b, hw >> 6, hw & 63);
        float cm = cmv * mr + mr;
        rmap[qid] = 1.0f / (1.0f + __expf(cm));
        cmapf[qid] = cm;
        outp[OUT_CM_OFF + qid] = cm;
    }
}

// K5A: 3x3 conv layer 1 with x1 = rmap*G + b_in fused into the tile load.
// og-split 8 -> grid 512. (k4 eliminated via pointwise identity)
__global__ void k5a_conv3(const float* __restrict__ G, const float* __restrict__ rmap,
                          const float* __restrict__ b_in, const float* __restrict__ w,
                          const float* __restrict__ bias, float* __restrict__ xout) {
    __shared__ float tile[32][324];
    __shared__ float wsm[1152];
    __shared__ float bsm[4];
    __shared__ float bin_s[32];
    int blk = blockIdx.x;
    int og = blk & 7;  blk >>= 3;
    int tx = blk & 3;  blk >>= 2;
    int ty = blk & 3;  blk >>= 2;
    int b  = blk;
    int tid = threadIdx.x;
    for (int i = tid; i < 1152; i += 256) wsm[i] = w[og * 1152 + i];
    if (tid < 4) bsm[tid] = bias[og * 4 + tid];
    if (tid < 32) bin_s[tid] = b_in[tid];
    __syncthreads();   // bin_s visible before tile load uses it
    int y0 = ty * 16 - 1, x0 = tx * 16 - 1;
    const float* rb = rmap + b * NN;
    for (int i = tid; i < 32 * 324; i += 256) {
        int c = i / 324, r = i % 324;
        int yy = r / 18, xx = r % 18;
        int gy = y0 + yy, gx = x0 + xx;
        float v = 0.0f;
        if (gy >= 0 && gy < 64 && gx >= 0 && gx < 64) {
            int p = gy * 64 + gx;
            v = fmaf(G[((size_t)b * CH + c) * NN + p], rb[p], bin_s[c]);
        }
        tile[c][r] = v;
    }
    __syncthreads();
    int py = tid >> 4, px = tid & 15;
    float acc[4];
    #pragma unroll
    for (int j = 0; j < 4; ++j) acc[j] = bsm[j];
    for (int i = 0; i < 32; ++i) {
        const float* tr = &tile[i][py * 18 + px];
        float v00 = tr[0],  v01 = tr[1],  v02 = tr[2];
        float v10 = tr[18], v11 = tr[19], v12 = tr[20];
        float v20 = tr[36], v21 = tr[37], v22 = tr[38];
        #pragma unroll
        for (int j = 0; j < 4; ++j) {
            const float* wj = &wsm[j * 288 + i * 9];
            acc[j] += v00 * wj[0] + v01 * wj[1] + v02 * wj[2]
                    + v10 * wj[3] + v11 * wj[4] + v12 * wj[5]
                    + v20 * wj[6] + v21 * wj[7] + v22 * wj[8];
        }
    }
    size_t base = (size_t)b * CH * NN + (size_t)(og * 4) * NN
                + (ty * 16 + py) * 64 + tx * 16 + px;
    #pragma unroll
    for (int j = 0; j < 4; ++j)
        xout[base + j * NN] = fmaxf(acc[j], 0.0f);
}

// K5: 3x3 conv 32->32 (+bias, relu). og-split 8 -> grid 512. (r12-r16 proven)
__global__ void k5_conv3(const float* __restrict__ xin, const float* __restrict__ w,
                         const float* __restrict__ bias, float* __restrict__ xout,
                         float* __restrict__ outx) {
    __shared__ float tile[32][324];
    __shared__ float wsm[1152];
    __shared__ float bsm[4];
    int blk = blockIdx.x;
    int og = blk & 7;  blk >>= 3;
    int tx = blk & 3;  blk >>= 2;
    int ty = blk & 3;  blk >>= 2;
    int b  = blk;
    int tid = threadIdx.x;
    for (int i = tid; i < 1152; i += 256) wsm[i] = w[og * 1152 + i];
    if (tid < 4) bsm[tid] = bias[og * 4 + tid];
    int y0 = ty * 16 - 1, x0 = tx * 16 - 1;
    for (int i = tid; i < 32 * 324; i += 256) {
        int c = i / 324, r = i % 324;
        int yy = r / 18, xx = r % 18;
        int gy = y0 + yy, gx = x0 + xx;
        float v = 0.0f;
        if (gy >= 0 && gy < 64 && gx >= 0 && gx < 64)
            v = xin[((size_t)b * CH + c) * NN + gy * 64 + gx];
        tile[c][r] = v;
    }
    __syncthreads();
    int py = tid >> 4, px = tid & 15;
    float acc[4];
    #pragma unroll
    for (int j = 0; j < 4; ++j) acc[j] = bsm[j];
    for (int i = 0; i < 32; ++i) {
        const float* tr = &tile[i][py * 18 + px];
        float v00 = tr[0],  v01 = tr[1],  v02 = tr[2];
        float v10 = tr[18], v11 = tr[19], v12 = tr[20];
        float v20 = tr[36], v21 = tr[37], v22 = tr[38];
        #pragma unroll
        for (int j = 0; j < 4; ++j) {
            const float* wj = &wsm[j * 288 + i * 9];
            acc[j] += v00 * wj[0] + v01 * wj[1] + v02 * wj[2]
                    + v10 * wj[3] + v11 * wj[4] + v12 * wj[5]
                    + v20 * wj[6] + v21 * wj[7] + v22 * wj[8];
        }
    }
    size_t base = (size_t)b * CH * NN + (size_t)(og * 4) * NN
                + (ty * 16 + py) * 64 + tx * 16 + px;
    #pragma unroll
    for (int j = 0; j < 4; ++j) {
        float r_ = fmaxf(acc[j], 0.0f);
        xout[base + j * NN] = r_;
        if (outx) outx[base + j * NN] = r_;
    }
}

// K6: final 3x3 conv 32->1 + b_out + corrected_map. channel-split 4x8, grid 256
__global__ void k6_convout(const float* __restrict__ xin, const float* __restrict__ w_out,
                           const float* __restrict__ b_out, const float* __restrict__ cmapf,
                           float* __restrict__ outp) {
    __shared__ float wsm[288];
    __shared__ float red[256];
    int tid = threadIdx.x;
    for (int i = tid; i < 288; i += 256) wsm[i] = w_out[i];
    int pxi = tid & 63, g = tid >> 6;
    int gid = blockIdx.x * 64 + pxi;
    int b = gid >> 12, hw = gid & 4095;
    int y = hw >> 6, x = hw & 63;
    __syncthreads();
    float acc = 0.0f;
    int c0 = g * 8;
    for (int i = c0; i < c0 + 8; ++i) {
        const float* xi = xin + ((size_t)b * CH + i) * NN;
        #pragma unroll
        for (int ky = 0; ky < 3; ++ky) {
            int gy = y + ky - 1;
            if (gy < 0 || gy > 63) continue;
            #pragma unroll
            for (int kx = 0; kx < 3; ++kx) {
                int gx = x + kx - 1;
                if (gx < 0 || gx > 63) continue;
                acc += xi[gy * 64 + gx] * wsm[i * 9 + ky * 3 + kx];
            }
        }
    }
    red[tid] = acc;
    __syncthreads();
    if (tid < 64) {
        float a = red[tid] + red[tid + 64] + red[tid + 128] + red[tid + 192]
                + b_out[0] + cmapf[gid];
        outp[OUT_O_OFF + gid] = a;
    }
}

extern "C" void kernel_launch(void* const* d_in, const int* in_sizes, int n_in,
                              void* d_out, int out_size, void* d_ws, size_t ws_size,
                              hipStream_t stream) {
    const float* f     = (const float*)d_in[0];
    const float* mapin = (const float*)d_in[1];
    const float* f_q   = (const float*)d_in[2];
    const float* f_k   = (const float*)d_in[3];
    const float* m_k   = (const float*)d_in[4];
    const float* wq    = (const float*)d_in[5];
    const float* wk    = (const float*)d_in[6];
    const float* w_in  = (const float*)d_in[7];
    const float* b_in  = (const float*)d_in[8];
    const float* w_mid = (const float*)d_in[9];
    const float* b_mid = (const float*)d_in[10];
    const float* w_out = (const float*)d_in[11];
    const float* b_out = (const float*)d_in[12];
    float* outp = (float*)d_out;
    float* ws = (float*)d_ws;

    float* Q4    = ws + Q4_OFF;
    float* K4    = ws + K4_OFF;
    float* RMAP  = ws + RMAP_OFF;
    float* CMAPF = ws + CMAPF_OFF;
    float* CPSUM = ws + CPSUM_OFF;
    float* T8    = ws + T8_OFF;
    float* G     = ws + G_OFF;
    float* XA    = ws + XA_OFF;
    float* XB    = ws + XB_OFF;

    k1g<<<512, 512, 0, stream>>>(f_q, f_k, wq, wk, f, w_in, Q4, K4, G);
    k2a_colstats<<<BB * NQCH * 8, 256, 0, stream>>>(Q4, K4, CPSUM);
    k3a_scan<<<BB * 16 * 32, 256, 0, stream>>>(Q4, K4, CPSUM, m_k, T8);
    k3b_merge<<<BB * NN / 4, 256, 0, stream>>>(T8, mapin, RMAP, CMAPF, outp);
    k5a_conv3<<<512, 256, 0, stream>>>(G, RMAP, b_in, w_mid + 0 * 9216, b_mid + 0 * 32, XB);
    k5_conv3<<<512, 256, 0, stream>>>(XB, w_mid + 1 * 9216, b_mid + 1 * 32, XA, (float*)0);
    k5_conv3<<<512, 256, 0, stream>>>(XA, w_mid + 2 * 9216, b_mid + 2 * 32, XB, outp + OUT_X_OFF);
    k6_convout<<<256, 256, 0, stream>>>(XB, w_out, b_out, CMAPF, outp);
}